// Round 1
// baseline (2244.892 us; speedup 1.0000x reference)
//
#include <hip/hip_runtime.h>
#include <math.h>

namespace {

constexpr int Bb   = 2;
constexpr int Ss   = 2048;
constexpr int Dd   = 1024;
constexpr int Hh   = 8;
constexpr int DKk  = 128;
constexpr int KTOP = 512;
constexpr int BH    = Bb * Hh;   // 16
constexpr int MROWS = Bb * Ss;   // 4096
constexpr float SCALE = 0.08838834764831845f;  // 1/sqrt(128)

__device__ inline void store_t(float (&Sarr)[16][64], int c4, int r, float4 v) {
  Sarr[c4 + 0][r] = v.x;
  Sarr[c4 + 1][r] = v.y;
  Sarr[c4 + 2][r] = v.z;
  Sarr[c4 + 3][r] = v.w;
}

#define FMA16(a, b)                                                                         \
  acc[0][0] += a.x * b.x; acc[0][1] += a.x * b.y; acc[0][2] += a.x * b.z; acc[0][3] += a.x * b.w; \
  acc[1][0] += a.y * b.x; acc[1][1] += a.y * b.y; acc[1][2] += a.y * b.z; acc[1][3] += a.y * b.w; \
  acc[2][0] += a.z * b.x; acc[2][1] += a.z * b.y; acc[2][2] += a.z * b.z; acc[2][3] += a.z * b.w; \
  acc[3][0] += a.w * b.x; acc[3][1] += a.w * b.y; acc[3][2] += a.w * b.z; acc[3][3] += a.w * b.w;

// ---------------------------------------------------------------------------
// 64x64-tile f32 NN GEMM: C[M x N] = A[M x Kd] @ B[Kd x N] + bias
// MODE 0: plain row-major write to out[M x N]
// MODE 1: scatter to [B,H,S,DK] layout (for Q/K/V projections)
// ---------------------------------------------------------------------------
template <int MODE>
__global__ __launch_bounds__(256) void gemm_nn(
    const float* __restrict__ A, const float* __restrict__ Bm,
    const float* __restrict__ bias, float* __restrict__ out,
    int Kd, int Ndim)
{
  __shared__ float As[16][64];  // [k][m]
  __shared__ float Bs[16][64];  // [k][n]
  const int t  = threadIdx.x;
  const int n0 = blockIdx.x * 64;
  const int m0 = blockIdx.y * 64;
  const int tx4 = (t & 15) << 2;
  const int ty4 = (t >> 4) << 2;
  const int ar = t >> 2,  ac4 = (t & 3) << 2;   // A-tile: 64 rows x 16 cols
  const int br = t >> 4,  bc4 = (t & 15) << 2;  // B-tile: 16 rows x 64 cols
  float acc[4][4] = {};

  for (int kt = 0; kt < Kd; kt += 16) {
    float4 av = *(const float4*)(A + (size_t)(m0 + ar) * Kd + kt + ac4);
    store_t(As, ac4, ar, av);
    *(float4*)&Bs[br][bc4] =
        *(const float4*)(Bm + (size_t)(kt + br) * Ndim + n0 + bc4);
    __syncthreads();
#pragma unroll
    for (int k = 0; k < 16; ++k) {
      float4 a = *(const float4*)&As[k][ty4];
      float4 b = *(const float4*)&Bs[k][tx4];
      FMA16(a, b)
    }
    __syncthreads();
  }

#pragma unroll
  for (int i = 0; i < 4; ++i) {
    const int m = m0 + ty4 + i;
#pragma unroll
    for (int j = 0; j < 4; ++j) {
      const int n = n0 + tx4 + j;
      const float v = acc[i][j] + bias[n];
      if (MODE == 0) {
        out[(size_t)m * Ndim + n] = v;
      } else {
        const int bb = m >> 11, s = m & (Ss - 1);
        const int hh = n >> 7,  dk = n & (DKk - 1);
        out[(((size_t)(bb * Hh + hh)) * Ss + s) * DKk + dk] = v;
      }
    }
  }
}

// ---------------------------------------------------------------------------
// Batched scores: C[q,j] = (1/sqrt(DK)) * sum_d Q[q,d] * K[j,d]   (NT GEMM)
// one batch per (b,h); written straight into the weights region of d_out
// ---------------------------------------------------------------------------
__global__ __launch_bounds__(256) void scores_nt(
    const float* __restrict__ Qw, const float* __restrict__ Kw,
    float* __restrict__ outw)
{
  __shared__ float As[16][64];  // [d][q]
  __shared__ float Bs[16][64];  // [d][j]
  const int t  = threadIdx.x;
  const int bh = blockIdx.z;
  const float* Qp = Qw + (size_t)bh * Ss * DKk;
  const float* Kp = Kw + (size_t)bh * Ss * DKk;
  float* C = outw + (size_t)bh * Ss * Ss;
  const int j0 = blockIdx.x * 64;
  const int q0 = blockIdx.y * 64;
  const int tx4 = (t & 15) << 2;
  const int ty4 = (t >> 4) << 2;
  const int r = t >> 2, c4 = (t & 3) << 2;
  float acc[4][4] = {};

  for (int kt = 0; kt < DKk; kt += 16) {
    float4 qv = *(const float4*)(Qp + (size_t)(q0 + r) * DKk + kt + c4);
    store_t(As, c4, r, qv);
    float4 kv = *(const float4*)(Kp + (size_t)(j0 + r) * DKk + kt + c4);
    store_t(Bs, c4, r, kv);
    __syncthreads();
#pragma unroll
    for (int k = 0; k < 16; ++k) {
      float4 a = *(const float4*)&As[k][ty4];
      float4 b = *(const float4*)&Bs[k][tx4];
      FMA16(a, b)
    }
    __syncthreads();
  }

#pragma unroll
  for (int i = 0; i < 4; ++i)
#pragma unroll
    for (int j = 0; j < 4; ++j)
      C[(size_t)(q0 + ty4 + i) * Ss + (j0 + tx4 + j)] = acc[i][j] * SCALE;
}

// ---------------------------------------------------------------------------
// Batched PV: attn_bh[q, dk] = sum_l W[q,l] * V[l,dk]   (NN GEMM, Kd = S)
// output scattered to attn[B,S,D] layout
// ---------------------------------------------------------------------------
__global__ __launch_bounds__(256) void pv_nn(
    const float* __restrict__ Wts, const float* __restrict__ Vw,
    float* __restrict__ attn)
{
  __shared__ float As[16][64];
  __shared__ float Bs[16][64];
  const int t  = threadIdx.x;
  const int bh = blockIdx.z;
  const int bb = bh >> 3, hh = bh & 7;
  const float* A  = Wts + (size_t)bh * Ss * Ss;   // [2048 x 2048]
  const float* Bv = Vw  + (size_t)bh * Ss * DKk;  // [2048 x 128]
  const int n0 = blockIdx.x * 64;
  const int m0 = blockIdx.y * 64;
  const int tx4 = (t & 15) << 2;
  const int ty4 = (t >> 4) << 2;
  const int ar = t >> 2,  ac4 = (t & 3) << 2;
  const int br = t >> 4,  bc4 = (t & 15) << 2;
  float acc[4][4] = {};

  for (int kt = 0; kt < Ss; kt += 16) {
    float4 av = *(const float4*)(A + (size_t)(m0 + ar) * Ss + kt + ac4);
    store_t(As, ac4, ar, av);
    *(float4*)&Bs[br][bc4] =
        *(const float4*)(Bv + (size_t)(kt + br) * DKk + n0 + bc4);
    __syncthreads();
#pragma unroll
    for (int k = 0; k < 16; ++k) {
      float4 a = *(const float4*)&As[k][ty4];
      float4 b = *(const float4*)&Bs[k][tx4];
      FMA16(a, b)
    }
    __syncthreads();
  }

#pragma unroll
  for (int i = 0; i < 4; ++i) {
    const int m = m0 + ty4 + i;  // q within batch
#pragma unroll
    for (int j = 0; j < 4; ++j) {
      const int n = n0 + tx4 + j;  // dk
      attn[((size_t)(bb * Ss + m)) * Dd + hh * DKk + n] = acc[i][j];
    }
  }
}

__device__ inline float key_to_float(unsigned k) {
  unsigned u = (k & 0x80000000u) ? (k & 0x7FFFFFFFu) : ~k;
  return __uint_as_float(u);
}

// ---------------------------------------------------------------------------
// Per-row exact top-512 (radix-256 select, jax tie-break by lowest index)
// + softmax over selected entries, rewritten in place as a dense row.
// One block (256 threads) per row; row length S=2048.
// ---------------------------------------------------------------------------
__global__ __launch_bounds__(256) void topk_softmax(float* __restrict__ wts)
{
  __shared__ float    vals[Ss];    // 8 KB
  __shared__ unsigned keys[Ss];    // 8 KB
  __shared__ unsigned hist[256];   // histogram, reused as max-reduce scratch
  __shared__ float    zs[256];     // sum-reduce scratch
  __shared__ unsigned sBin, sNeedK;

  const int t = threadIdx.x;
  float* rowp = wts + (size_t)blockIdx.x * Ss;

  for (int i = t; i < Ss; i += 256) {
    const float v = rowp[i];
    vals[i] = v;
    const unsigned u = __float_as_uint(v);
    keys[i] = (u & 0x80000000u) ? ~u : (u | 0x80000000u);  // order-preserving
  }
  __syncthreads();

  unsigned prefix = 0, maskHi = 0, needK = KTOP;
#pragma unroll
  for (int pass = 0; pass < 4; ++pass) {
    const int shift = 24 - 8 * pass;
    hist[t] = 0;
    __syncthreads();
    for (int i = t; i < Ss; i += 256) {
      const unsigned k = keys[i];
      if ((k & maskHi) == prefix) atomicAdd(&hist[(k >> shift) & 255u], 1u);
    }
    __syncthreads();
    if (t == 0) {
      unsigned c = 0, bin = 0, nk = needK;
      for (int b = 255; b >= 0; --b) {
        const unsigned h = hist[b];
        if (c + h >= needK) { bin = (unsigned)b; nk = needK - c; break; }
        c += h;
      }
      sBin = bin; sNeedK = nk;
    }
    __syncthreads();
    prefix |= sBin << shift;
    needK   = sNeedK;
    maskHi |= 0xFFu << shift;
    __syncthreads();
  }
  const unsigned T = prefix;  // exact bits of the 512-th largest value

  // row max (the max is always selected)
  unsigned lmax = 0;
  for (int i = t; i < Ss; i += 256) {
    const unsigned k = keys[i];
    lmax = (k > lmax) ? k : lmax;
  }
  __syncthreads();
  hist[t] = lmax;
  __syncthreads();
  for (int s2 = 128; s2 > 0; s2 >>= 1) {
    if (t < s2) { const unsigned o = hist[t + s2]; if (o > hist[t]) hist[t] = o; }
    __syncthreads();
  }
  const float m  = key_to_float(hist[0]);
  const float vT = key_to_float(T);
  const float eT = expf(vT - m);

  // Z = sum over strictly-greater + needK copies of the threshold value
  float lz = 0.f;
  for (int i = t; i < Ss; i += 256)
    if (keys[i] > T) lz += expf(vals[i] - m);
  zs[t] = lz;
  __syncthreads();
  for (int s2 = 128; s2 > 0; s2 >>= 1) {
    if (t < s2) zs[t] += zs[t + s2];
    __syncthreads();
  }
  const float Z    = zs[0] + (float)needK * eT;
  const float Zinv = 1.0f / Z;

  for (int i = t; i < Ss; i += 256) {
    const unsigned k = keys[i];
    float w = 0.f;
    if (k > T) {
      w = expf(vals[i] - m) * Zinv;
    } else if (k == T) {
      unsigned rank = 0;
      for (int j = 0; j < i; ++j) rank += (keys[j] == T);  // ties: lowest index first
      if (rank < needK) w = eT * Zinv;
    }
    rowp[i] = w;
  }
}

}  // namespace

extern "C" void kernel_launch(void* const* d_in, const int* in_sizes, int n_in,
                              void* d_out_v, int out_size, void* d_ws, size_t ws_size,
                              hipStream_t stream)
{
  const float* query = (const float*)d_in[0];
  const float* key   = (const float*)d_in[1];
  const float* value = (const float*)d_in[2];
  const float* Wq = (const float*)d_in[3];  const float* bq = (const float*)d_in[4];
  const float* Wk = (const float*)d_in[5];  const float* bk = (const float*)d_in[6];
  const float* Wv = (const float*)d_in[7];  const float* bv = (const float*)d_in[8];
  const float* Wo = (const float*)d_in[9];  const float* bo = (const float*)d_in[10];

  float* d_out = (float*)d_out_v;
  float* outp  = d_out;                              // [B,S,D]
  float* wts   = d_out + (size_t)Bb * Ss * Dd;       // [B,H,S,S]

  float* ws   = (float*)d_ws;
  float* Q    = ws;                                  // [B,H,S,DK]
  float* K    = Q + (size_t)BH * Ss * DKk;
  float* V    = K + (size_t)BH * Ss * DKk;
  float* attn = V + (size_t)BH * Ss * DKk;           // [B,S,D]

  const dim3 blk(256);

  // 1) projections (f32, precision-critical for Q/K)
  const dim3 gproj(Dd / 64, MROWS / 64);
  gemm_nn<1><<<gproj, blk, 0, stream>>>(query, Wq, bq, Q, Dd, Dd);
  gemm_nn<1><<<gproj, blk, 0, stream>>>(key,   Wk, bk, K, Dd, Dd);
  gemm_nn<1><<<gproj, blk, 0, stream>>>(value, Wv, bv, V, Dd, Dd);

  // 2) scores -> weights region of d_out (scaled)
  const dim3 gsc(Ss / 64, Ss / 64, BH);
  scores_nt<<<gsc, blk, 0, stream>>>(Q, K, wts);

  // 3) exact top-512 + softmax, in place
  topk_softmax<<<dim3(BH * Ss), blk, 0, stream>>>(wts);

  // 4) PV
  const dim3 gpv(DKk / 64, Ss / 64, BH);
  pv_nn<<<gpv, blk, 0, stream>>>(wts, V, attn);

  // 5) output projection
  gemm_nn<0><<<gproj, blk, 0, stream>>>(attn, Wo, bo, outp, Dd, Dd);
}

// Round 2
// 1174.864 us; speedup vs baseline: 1.9108x; 1.9108x over previous
//
#include <hip/hip_runtime.h>
#include <math.h>

namespace {

constexpr int Bb   = 2;
constexpr int Ss   = 2048;
constexpr int Dd   = 1024;
constexpr int Hh   = 8;
constexpr int DKk  = 128;
constexpr int KTOP = 512;
constexpr int BH    = Bb * Hh;   // 16
constexpr int MROWS = Bb * Ss;   // 4096
constexpr float SCALE = 0.08838834764831845f;  // 1/sqrt(128)

__device__ inline void store_t(float (&Sarr)[16][64], int c4, int r, float4 v) {
  Sarr[c4 + 0][r] = v.x;
  Sarr[c4 + 1][r] = v.y;
  Sarr[c4 + 2][r] = v.z;
  Sarr[c4 + 3][r] = v.w;
}

#define FMA16(a, b)                                                                         \
  acc[0][0] += a.x * b.x; acc[0][1] += a.x * b.y; acc[0][2] += a.x * b.z; acc[0][3] += a.x * b.w; \
  acc[1][0] += a.y * b.x; acc[1][1] += a.y * b.y; acc[1][2] += a.y * b.z; acc[1][3] += a.y * b.w; \
  acc[2][0] += a.z * b.x; acc[2][1] += a.z * b.y; acc[2][2] += a.z * b.z; acc[2][3] += a.z * b.w; \
  acc[3][0] += a.w * b.x; acc[3][1] += a.w * b.y; acc[3][2] += a.w * b.z; acc[3][3] += a.w * b.w;

// ---------------------------------------------------------------------------
// 64x64-tile f32 NN GEMM: C[M x N] = A[M x Kd] @ B[Kd x N] + bias
// MODE 0: plain row-major write to out[M x N]
// MODE 1: scatter to [B,H,S,DK] layout (for Q/K/V projections)
// ---------------------------------------------------------------------------
template <int MODE>
__global__ __launch_bounds__(256) void gemm_nn(
    const float* __restrict__ A, const float* __restrict__ Bm,
    const float* __restrict__ bias, float* __restrict__ out,
    int Kd, int Ndim)
{
  __shared__ float As[16][64];  // [k][m]
  __shared__ float Bs[16][64];  // [k][n]
  const int t  = threadIdx.x;
  const int n0 = blockIdx.x * 64;
  const int m0 = blockIdx.y * 64;
  const int tx4 = (t & 15) << 2;
  const int ty4 = (t >> 4) << 2;
  const int ar = t >> 2,  ac4 = (t & 3) << 2;   // A-tile: 64 rows x 16 cols
  const int br = t >> 4,  bc4 = (t & 15) << 2;  // B-tile: 16 rows x 64 cols
  float acc[4][4] = {};

  for (int kt = 0; kt < Kd; kt += 16) {
    float4 av = *(const float4*)(A + (size_t)(m0 + ar) * Kd + kt + ac4);
    store_t(As, ac4, ar, av);
    *(float4*)&Bs[br][bc4] =
        *(const float4*)(Bm + (size_t)(kt + br) * Ndim + n0 + bc4);
    __syncthreads();
#pragma unroll
    for (int k = 0; k < 16; ++k) {
      float4 a = *(const float4*)&As[k][ty4];
      float4 b = *(const float4*)&Bs[k][tx4];
      FMA16(a, b)
    }
    __syncthreads();
  }

#pragma unroll
  for (int i = 0; i < 4; ++i) {
    const int m = m0 + ty4 + i;
#pragma unroll
    for (int j = 0; j < 4; ++j) {
      const int n = n0 + tx4 + j;
      const float v = acc[i][j] + bias[n];
      if (MODE == 0) {
        out[(size_t)m * Ndim + n] = v;
      } else {
        const int bb = m >> 11, s = m & (Ss - 1);
        const int hh = n >> 7,  dk = n & (DKk - 1);
        out[(((size_t)(bb * Hh + hh)) * Ss + s) * DKk + dk] = v;
      }
    }
  }
}

// ---------------------------------------------------------------------------
// Batched scores: C[q,j] = (1/sqrt(DK)) * sum_d Q[q,d] * K[j,d]   (NT GEMM)
// ---------------------------------------------------------------------------
__global__ __launch_bounds__(256) void scores_nt(
    const float* __restrict__ Qw, const float* __restrict__ Kw,
    float* __restrict__ outw)
{
  __shared__ float As[16][64];  // [d][q]
  __shared__ float Bs[16][64];  // [d][j]
  const int t  = threadIdx.x;
  const int bh = blockIdx.z;
  const float* Qp = Qw + (size_t)bh * Ss * DKk;
  const float* Kp = Kw + (size_t)bh * Ss * DKk;
  float* C = outw + (size_t)bh * Ss * Ss;
  const int j0 = blockIdx.x * 64;
  const int q0 = blockIdx.y * 64;
  const int tx4 = (t & 15) << 2;
  const int ty4 = (t >> 4) << 2;
  const int r = t >> 2, c4 = (t & 3) << 2;
  float acc[4][4] = {};

  for (int kt = 0; kt < DKk; kt += 16) {
    float4 qv = *(const float4*)(Qp + (size_t)(q0 + r) * DKk + kt + c4);
    store_t(As, c4, r, qv);
    float4 kv = *(const float4*)(Kp + (size_t)(j0 + r) * DKk + kt + c4);
    store_t(Bs, c4, r, kv);
    __syncthreads();
#pragma unroll
    for (int k = 0; k < 16; ++k) {
      float4 a = *(const float4*)&As[k][ty4];
      float4 b = *(const float4*)&Bs[k][tx4];
      FMA16(a, b)
    }
    __syncthreads();
  }

#pragma unroll
  for (int i = 0; i < 4; ++i)
#pragma unroll
    for (int j = 0; j < 4; ++j)
      C[(size_t)(q0 + ty4 + i) * Ss + (j0 + tx4 + j)] = acc[i][j] * SCALE;
}

// ---------------------------------------------------------------------------
// Batched PV: attn_bh[q, dk] = sum_l W[q,l] * V[l,dk]   (NN GEMM, Kd = S)
// ---------------------------------------------------------------------------
__global__ __launch_bounds__(256) void pv_nn(
    const float* __restrict__ Wts, const float* __restrict__ Vw,
    float* __restrict__ attn)
{
  __shared__ float As[16][64];
  __shared__ float Bs[16][64];
  const int t  = threadIdx.x;
  const int bh = blockIdx.z;
  const int bb = bh >> 3, hh = bh & 7;
  const float* A  = Wts + (size_t)bh * Ss * Ss;   // [2048 x 2048]
  const float* Bv = Vw  + (size_t)bh * Ss * DKk;  // [2048 x 128]
  const int n0 = blockIdx.x * 64;
  const int m0 = blockIdx.y * 64;
  const int tx4 = (t & 15) << 2;
  const int ty4 = (t >> 4) << 2;
  const int ar = t >> 2,  ac4 = (t & 3) << 2;
  const int br = t >> 4,  bc4 = (t & 15) << 2;
  float acc[4][4] = {};

  for (int kt = 0; kt < Ss; kt += 16) {
    float4 av = *(const float4*)(A + (size_t)(m0 + ar) * Ss + kt + ac4);
    store_t(As, ac4, ar, av);
    *(float4*)&Bs[br][bc4] =
        *(const float4*)(Bv + (size_t)(kt + br) * DKk + n0 + bc4);
    __syncthreads();
#pragma unroll
    for (int k = 0; k < 16; ++k) {
      float4 a = *(const float4*)&As[k][ty4];
      float4 b = *(const float4*)&Bs[k][tx4];
      FMA16(a, b)
    }
    __syncthreads();
  }

#pragma unroll
  for (int i = 0; i < 4; ++i) {
    const int m = m0 + ty4 + i;  // q within batch
#pragma unroll
    for (int j = 0; j < 4; ++j) {
      const int n = n0 + tx4 + j;  // dk
      attn[((size_t)(bb * Ss + m)) * Dd + hh * DKk + n] = acc[i][j];
    }
  }
}

__device__ inline unsigned key_of(float v) {
  const unsigned u = __float_as_uint(v);
  return (u & 0x80000000u) ? ~u : (u | 0x80000000u);  // order-preserving flip
}
__device__ inline float key_to_float(unsigned k) {
  const unsigned u = (k & 0x80000000u) ? (k & 0x7FFFFFFFu) : ~k;
  return __uint_as_float(u);
}

// ---------------------------------------------------------------------------
// Per-row exact top-512 (radix-256 select) + softmax, in place.
// Fully parallel: shuffle-scan suffix sums instead of serial t==0 bin scan;
// tie ranking only on the (rare) exact-duplicate-straddle path.
// One block (256 threads = 4 waves) per row; row length S=2048.
// ---------------------------------------------------------------------------
__global__ __launch_bounds__(256) void topk_softmax(float* __restrict__ wts)
{
  __shared__ unsigned keys[Ss];    // 8 KB
  __shared__ unsigned hist[256];
  __shared__ unsigned wred[4];
  __shared__ float    fred[4];
  __shared__ unsigned sBin, sNeedK, sTie;

  const int t    = threadIdx.x;
  const int lane = t & 63;
  const int wv   = t >> 6;
  float* rowp = wts + (size_t)blockIdx.x * Ss;

  // ---- load row, build order-flipped keys, fold in running max ----
  unsigned lmax = 0u;
#pragma unroll
  for (int base = 0; base < Ss; base += 1024) {
    const float4 v = *(const float4*)(rowp + base + 4 * t);
    uint4 k;
    k.x = key_of(v.x); k.y = key_of(v.y); k.z = key_of(v.z); k.w = key_of(v.w);
    lmax = max(max(lmax, max(k.x, k.y)), max(k.z, k.w));
    *(uint4*)&keys[base + 4 * t] = k;
  }
#pragma unroll
  for (int off = 32; off > 0; off >>= 1) {
    const unsigned o = __shfl_xor(lmax, off);
    lmax = max(lmax, o);
  }
  if (lane == 0) wred[wv] = lmax;
  __syncthreads();
  const float m = key_to_float(max(max(wred[0], wred[1]), max(wred[2], wred[3])));

  // ---- 4-pass radix-256 select of the 512-th largest key ----
  unsigned prefix = 0u, maskHi = 0u, needK = KTOP, tieC = 0u;
#pragma unroll
  for (int pass = 0; pass < 4; ++pass) {
    const int shift = 24 - 8 * pass;
    hist[t] = 0u;
    __syncthreads();
    for (int i = t; i < Ss; i += 256) {
      const unsigned k = keys[i];
      if ((k & maskHi) == prefix) atomicAdd(&hist[(k >> shift) & 255u], 1u);
    }
    __syncthreads();
    const unsigned h = hist[t];      // this thread's bin count (bin == t)
    unsigned s = h;                  // intra-wave inclusive suffix sum
#pragma unroll
    for (int off = 1; off < 64; off <<= 1) {
      const unsigned v = __shfl_down(s, off);
      if (lane + off < 64) s += v;
    }
    if (lane == 0) wred[wv] = s;     // wave totals
    __syncthreads();
    unsigned stot = s;
    for (int w2 = wv + 1; w2 < 4; ++w2) stot += wred[w2];
    // threshold bin: suffix incl. this bin crosses needK
    if (h > 0u && stot >= needK && stot - h < needK) {
      sBin = (unsigned)t;
      sNeedK = needK - (stot - h);
      sTie = h;
    }
    __syncthreads();
    prefix |= sBin << shift;
    needK = sNeedK;
    tieC  = sTie;
    maskHi |= 0xFFu << shift;
    __syncthreads();
  }
  const unsigned T = prefix;  // exact bits of the 512-th largest value

  // ---- rare path: duplicates of T straddle the boundary -> rank by index ----
  if (tieC != needK) {
    if (t == 0) {
      unsigned taken = 0u;
      for (int i = 0; i < Ss; ++i)
        if (keys[i] == T) { if (taken < needK) ++taken; else keys[i] = 0u; }
    }
    __syncthreads();
  }

  // ---- softmax over selected entries ----
  const float eT = __expf(key_to_float(T) - m);
  float lz = 0.f;
  for (int i = t; i < Ss; i += 256) {
    const unsigned k = keys[i];
    if (k > T) lz += __expf(key_to_float(k) - m);
  }
#pragma unroll
  for (int off = 32; off > 0; off >>= 1) lz += __shfl_xor(lz, off);
  if (lane == 0) fred[wv] = lz;
  __syncthreads();
  const float Zi  = 1.0f / (fred[0] + fred[1] + fred[2] + fred[3] + (float)needK * eT);
  const float eTZ = eT * Zi;

#pragma unroll
  for (int base = 0; base < Ss; base += 1024) {
    const int i0 = base + 4 * t;
    float4 w;
    float* wp = &w.x;
#pragma unroll
    for (int j = 0; j < 4; ++j) {
      const unsigned k = keys[i0 + j];
      wp[j] = (k > T) ? __expf(key_to_float(k) - m) * Zi : ((k == T) ? eTZ : 0.f);
    }
    *(float4*)(rowp + i0) = w;
  }
}

}  // namespace

extern "C" void kernel_launch(void* const* d_in, const int* in_sizes, int n_in,
                              void* d_out_v, int out_size, void* d_ws, size_t ws_size,
                              hipStream_t stream)
{
  const float* query = (const float*)d_in[0];
  const float* key   = (const float*)d_in[1];
  const float* value = (const float*)d_in[2];
  const float* Wq = (const float*)d_in[3];  const float* bq = (const float*)d_in[4];
  const float* Wk = (const float*)d_in[5];  const float* bk = (const float*)d_in[6];
  const float* Wv = (const float*)d_in[7];  const float* bv = (const float*)d_in[8];
  const float* Wo = (const float*)d_in[9];  const float* bo = (const float*)d_in[10];

  float* d_out = (float*)d_out_v;
  float* outp  = d_out;                              // [B,S,D]
  float* wts   = d_out + (size_t)Bb * Ss * Dd;       // [B,H,S,S]

  float* ws   = (float*)d_ws;
  float* Q    = ws;                                  // [B,H,S,DK]
  float* K    = Q + (size_t)BH * Ss * DKk;
  float* V    = K + (size_t)BH * Ss * DKk;
  float* attn = V + (size_t)BH * Ss * DKk;           // [B,S,D]

  const dim3 blk(256);

  // 1) projections (f32, precision-critical for Q/K)
  const dim3 gproj(Dd / 64, MROWS / 64);
  gemm_nn<1><<<gproj, blk, 0, stream>>>(query, Wq, bq, Q, Dd, Dd);
  gemm_nn<1><<<gproj, blk, 0, stream>>>(key,   Wk, bk, K, Dd, Dd);
  gemm_nn<1><<<gproj, blk, 0, stream>>>(value, Wv, bv, V, Dd, Dd);

  // 2) scores -> weights region of d_out (scaled)
  const dim3 gsc(Ss / 64, Ss / 64, BH);
  scores_nt<<<gsc, blk, 0, stream>>>(Q, K, wts);

  // 3) exact top-512 + softmax, in place
  topk_softmax<<<dim3(BH * Ss), blk, 0, stream>>>(wts);

  // 4) PV
  const dim3 gpv(DKk / 64, Ss / 64, BH);
  pv_nn<<<gpv, blk, 0, stream>>>(wts, V, attn);

  // 5) output projection
  gemm_nn<0><<<gproj, blk, 0, stream>>>(attn, Wo, bo, outp, Dd, Dd);
}

// Round 3
// 824.799 us; speedup vs baseline: 2.7217x; 1.4244x over previous
//
#include <hip/hip_runtime.h>
#include <hip/hip_bf16.h>
#include <math.h>

namespace {

constexpr int Bb   = 2;
constexpr int Ss   = 2048;
constexpr int Dd   = 1024;
constexpr int Hh   = 8;
constexpr int DKk  = 128;
constexpr int KTOP = 512;
constexpr int BH    = Bb * Hh;   // 16
constexpr int MROWS = Bb * Ss;   // 4096
constexpr float SCALE = 0.08838834764831845f;  // 1/sqrt(128)

typedef __attribute__((ext_vector_type(8))) short short8t;  // 8 bf16 = 16 B
typedef __attribute__((ext_vector_type(4))) short short4t;  // 4 bf16 = 8 B
typedef __attribute__((ext_vector_type(4))) float f32x4;

__device__ inline ushort f2bf(float x) {  // f32 -> bf16 RNE
  const unsigned u = __float_as_uint(x);
  return (ushort)((u + 0x7FFFu + ((u >> 16) & 1u)) >> 16);
}

__device__ inline void store_t(float (&Sarr)[16][64], int c4, int r, float4 v) {
  Sarr[c4 + 0][r] = v.x;
  Sarr[c4 + 1][r] = v.y;
  Sarr[c4 + 2][r] = v.z;
  Sarr[c4 + 3][r] = v.w;
}

#define FMA16(a, b)                                                                         \
  acc[0][0] += a.x * b.x; acc[0][1] += a.x * b.y; acc[0][2] += a.x * b.z; acc[0][3] += a.x * b.w; \
  acc[1][0] += a.y * b.x; acc[1][1] += a.y * b.y; acc[1][2] += a.y * b.z; acc[1][3] += a.y * b.w; \
  acc[2][0] += a.z * b.x; acc[2][1] += a.z * b.y; acc[2][2] += a.z * b.z; acc[2][3] += a.z * b.w; \
  acc[3][0] += a.w * b.x; acc[3][1] += a.w * b.y; acc[3][2] += a.w * b.z; acc[3][3] += a.w * b.w;

// ---------------------------------------------------------------------------
// f32 NN GEMM (64x64 tile) — kept ONLY for Q/K projections (precision-critical)
// MODE 1: scatter to [B,H,S,DK] layout
// ---------------------------------------------------------------------------
template <int MODE>
__global__ __launch_bounds__(256) void gemm_nn(
    const float* __restrict__ A, const float* __restrict__ Bm,
    const float* __restrict__ bias, float* __restrict__ out,
    int Kd, int Ndim)
{
  __shared__ float As[16][64];  // [k][m]
  __shared__ float Bs[16][64];  // [k][n]
  const int t  = threadIdx.x;
  const int n0 = blockIdx.x * 64;
  const int m0 = blockIdx.y * 64;
  const int tx4 = (t & 15) << 2;
  const int ty4 = (t >> 4) << 2;
  const int ar = t >> 2,  ac4 = (t & 3) << 2;
  const int br = t >> 4,  bc4 = (t & 15) << 2;
  float acc[4][4] = {};

  for (int kt = 0; kt < Kd; kt += 16) {
    float4 av = *(const float4*)(A + (size_t)(m0 + ar) * Kd + kt + ac4);
    store_t(As, ac4, ar, av);
    *(float4*)&Bs[br][bc4] =
        *(const float4*)(Bm + (size_t)(kt + br) * Ndim + n0 + bc4);
    __syncthreads();
#pragma unroll
    for (int k = 0; k < 16; ++k) {
      float4 a = *(const float4*)&As[k][ty4];
      float4 b = *(const float4*)&Bs[k][tx4];
      FMA16(a, b)
    }
    __syncthreads();
  }

#pragma unroll
  for (int i = 0; i < 4; ++i) {
    const int m = m0 + ty4 + i;
#pragma unroll
    for (int j = 0; j < 4; ++j) {
      const int n = n0 + tx4 + j;
      const float v = acc[i][j] + bias[n];
      if (MODE == 0) {
        out[(size_t)m * Ndim + n] = v;
      } else {
        const int bb = m >> 11, s = m & (Ss - 1);
        const int hh = n >> 7,  dk = n & (DKk - 1);
        out[(((size_t)(bb * Hh + hh)) * Ss + s) * DKk + dk] = v;
      }
    }
  }
}

// ---------------------------------------------------------------------------
// Batched scores: C[q,j] = (1/sqrt(DK)) * sum_d Q[q,d] * K[j,d]   (f32 NT)
// ---------------------------------------------------------------------------
__global__ __launch_bounds__(256) void scores_nt(
    const float* __restrict__ Qw, const float* __restrict__ Kw,
    float* __restrict__ outw)
{
  __shared__ float As[16][64];  // [d][q]
  __shared__ float Bs[16][64];  // [d][j]
  const int t  = threadIdx.x;
  const int bh = blockIdx.z;
  const float* Qp = Qw + (size_t)bh * Ss * DKk;
  const float* Kp = Kw + (size_t)bh * Ss * DKk;
  float* C = outw + (size_t)bh * Ss * Ss;
  const int j0 = blockIdx.x * 64;
  const int q0 = blockIdx.y * 64;
  const int tx4 = (t & 15) << 2;
  const int ty4 = (t >> 4) << 2;
  const int r = t >> 2, c4 = (t & 3) << 2;
  float acc[4][4] = {};

  for (int kt = 0; kt < DKk; kt += 16) {
    float4 qv = *(const float4*)(Qp + (size_t)(q0 + r) * DKk + kt + c4);
    store_t(As, c4, r, qv);
    float4 kv = *(const float4*)(Kp + (size_t)(j0 + r) * DKk + kt + c4);
    store_t(Bs, c4, r, kv);
    __syncthreads();
#pragma unroll
    for (int k = 0; k < 16; ++k) {
      float4 a = *(const float4*)&As[k][ty4];
      float4 b = *(const float4*)&Bs[k][tx4];
      FMA16(a, b)
    }
    __syncthreads();
  }

#pragma unroll
  for (int i = 0; i < 4; ++i)
#pragma unroll
    for (int j = 0; j < 4; ++j)
      C[(size_t)(q0 + ty4 + i) * Ss + (j0 + tx4 + j)] = acc[i][j] * SCALE;
}

// ---------------------------------------------------------------------------
// bf16 MFMA NT GEMM: C[M x N] = A[M x K] @ Bt[N x K]^T  (+bias)
// 128x128 tile, BK=64, 4 waves (each 64x64), 16x16x32 bf16 MFMA.
// LDS tiles [row][k] with XOR swizzle on 16B granules: g ^= (row & 7).
// MODE 0: o_proj — A bf16, out f32 row-major [M x N], +bias
// MODE 1: v_proj — A bf16, out bf16 scatter Vt[bh][dk][s], +bias
// MODE 2: pv     — A f32 (weights, batched z=bh), out bf16 attn[B,S,D]
// ---------------------------------------------------------------------------
template <int MODE>
__global__ __launch_bounds__(256) void mfma_nt(
    const void* __restrict__ Ain, const ushort* __restrict__ BtAll,
    const float* __restrict__ bias, void* __restrict__ Cout,
    int M, int N, int K)
{
  __shared__ ushort As[128 * 64];  // 16 KB
  __shared__ ushort Bs[128 * 64];  // 16 KB
  const int t  = threadIdx.x;
  const int z  = blockIdx.z;
  const int n0 = blockIdx.x * 128;
  const int m0 = blockIdx.y * 128;
  const int l  = t & 63, wv = t >> 6;
  const int wr = wv >> 1, wc = wv & 1;     // wave's 64x64 quadrant
  const int lrow = l & 15, lhi = l >> 4;   // fragment lane decomposition

  const float*  Af = (MODE == 2) ? ((const float*)Ain) + (size_t)z * Ss * Ss : nullptr;
  const ushort* Ab = (MODE == 2) ? nullptr : (const ushort*)Ain;
  const ushort* Bt = (MODE == 2) ? BtAll + (size_t)z * DKk * Ss : BtAll;

  f32x4 acc[4][4] = {};

  for (int kt = 0; kt < K; kt += 64) {
#pragma unroll
    for (int p = 0; p < 4; ++p) {
      const int li = p * 256 + t, row = li >> 3, g = li & 7;
      const int sw = row * 64 + ((g ^ (row & 7)) << 3);
      short8t sa;
      if constexpr (MODE == 2) {
        const float* src = Af + (size_t)(m0 + row) * K + kt + g * 8;
        const float4 v0 = *(const float4*)src;
        const float4 v1 = *(const float4*)(src + 4);
        sa[0] = (short)f2bf(v0.x); sa[1] = (short)f2bf(v0.y);
        sa[2] = (short)f2bf(v0.z); sa[3] = (short)f2bf(v0.w);
        sa[4] = (short)f2bf(v1.x); sa[5] = (short)f2bf(v1.y);
        sa[6] = (short)f2bf(v1.z); sa[7] = (short)f2bf(v1.w);
      } else {
        sa = *(const short8t*)(Ab + (size_t)(m0 + row) * K + kt + g * 8);
      }
      *(short8t*)&As[sw] = sa;
      const short8t sb = *(const short8t*)(Bt + (size_t)(n0 + row) * K + kt + g * 8);
      *(short8t*)&Bs[sw] = sb;
    }
    __syncthreads();

#pragma unroll
    for (int kk = 0; kk < 2; ++kk) {
      short8t a[4], b[4];
      const int g = kk * 4 + lhi;
#pragma unroll
      for (int i = 0; i < 4; ++i) {
        const int row = wr * 64 + i * 16 + lrow;
        a[i] = *(const short8t*)&As[row * 64 + ((g ^ (row & 7)) << 3)];
      }
#pragma unroll
      for (int j = 0; j < 4; ++j) {
        const int row = wc * 64 + j * 16 + lrow;
        b[j] = *(const short8t*)&Bs[row * 64 + ((g ^ (row & 7)) << 3)];
      }
#pragma unroll
      for (int i = 0; i < 4; ++i)
#pragma unroll
        for (int j = 0; j < 4; ++j)
          acc[i][j] = __builtin_amdgcn_mfma_f32_16x16x32_bf16(a[i], b[j], acc[i][j], 0, 0, 0);
    }
    __syncthreads();
  }

  // epilogue: C/D layout col=lane&15, row=(lane>>4)*4+reg
#pragma unroll
  for (int i = 0; i < 4; ++i) {
#pragma unroll
    for (int j = 0; j < 4; ++j) {
      const int nn = n0 + wc * 64 + j * 16 + lrow;
#pragma unroll
      for (int r = 0; r < 4; ++r) {
        const int mm = m0 + wr * 64 + i * 16 + lhi * 4 + r;
        const float v = acc[i][j][r];
        if constexpr (MODE == 0) {
          ((float*)Cout)[(size_t)mm * N + nn] = v + bias[nn];
        } else if constexpr (MODE == 1) {
          const int bb = mm >> 11, s = mm & (Ss - 1);
          const int hh = nn >> 7,  dk = nn & (DKk - 1);
          ((ushort*)Cout)[((size_t)((bb * Hh + hh) * DKk + dk)) * Ss + s] =
              f2bf(v + bias[nn]);
        } else {
          const int bb = z >> 3, hh = z & 7;
          ((ushort*)Cout)[((size_t)(bb * Ss + mm)) * Dd + hh * DKk + nn] = f2bf(v);
        }
      }
    }
  }
}

// ---------------------------------------------------------------------------
// f32 -> bf16 elementwise conversion
// ---------------------------------------------------------------------------
__global__ __launch_bounds__(256) void conv_bf16(
    const float* __restrict__ in, ushort* __restrict__ out, int n)
{
  const int i = (blockIdx.x * 256 + threadIdx.x) * 4;
  if (i < n) {
    const float4 v = *(const float4*)(in + i);
    short4t o;
    o.x = (short)f2bf(v.x); o.y = (short)f2bf(v.y);
    o.z = (short)f2bf(v.z); o.w = (short)f2bf(v.w);
    *(short4t*)(out + i) = o;
  }
}

// ---------------------------------------------------------------------------
// W[1024][1024] f32 -> Wt[1024][1024] bf16 (transposed)
// ---------------------------------------------------------------------------
__global__ __launch_bounds__(256) void transpose_bf16(
    const float* __restrict__ W, ushort* __restrict__ Wt)
{
  __shared__ float tile[32][33];
  const int t  = threadIdx.x;
  const int c0 = blockIdx.x * 32, r0 = blockIdx.y * 32;
  const int lr = t >> 3, lc4 = (t & 7) * 4;
  const float4 v = *(const float4*)(W + (size_t)(r0 + lr) * Dd + c0 + lc4);
  tile[lr][lc4 + 0] = v.x; tile[lr][lc4 + 1] = v.y;
  tile[lr][lc4 + 2] = v.z; tile[lr][lc4 + 3] = v.w;
  __syncthreads();
  const int oc = t >> 3, or4 = (t & 7) * 4;
  short4t o;
  o.x = (short)f2bf(tile[or4 + 0][oc]);
  o.y = (short)f2bf(tile[or4 + 1][oc]);
  o.z = (short)f2bf(tile[or4 + 2][oc]);
  o.w = (short)f2bf(tile[or4 + 3][oc]);
  *(short4t*)(Wt + (size_t)(c0 + oc) * Dd + r0 + or4) = o;
}

__device__ inline unsigned key_of(float v) {
  const unsigned u = __float_as_uint(v);
  return (u & 0x80000000u) ? ~u : (u | 0x80000000u);
}
__device__ inline float key_to_float(unsigned k) {
  const unsigned u = (k & 0x80000000u) ? (k & 0x7FFFFFFFu) : ~k;
  return __uint_as_float(u);
}

// ---------------------------------------------------------------------------
// Per-row exact top-512 (radix-256 select) + softmax, in place. (unchanged)
// ---------------------------------------------------------------------------
__global__ __launch_bounds__(256) void topk_softmax(float* __restrict__ wts)
{
  __shared__ unsigned keys[Ss];
  __shared__ unsigned hist[256];
  __shared__ unsigned wred[4];
  __shared__ float    fred[4];
  __shared__ unsigned sBin, sNeedK, sTie;

  const int t    = threadIdx.x;
  const int lane = t & 63;
  const int wv   = t >> 6;
  float* rowp = wts + (size_t)blockIdx.x * Ss;

  unsigned lmax = 0u;
#pragma unroll
  for (int base = 0; base < Ss; base += 1024) {
    const float4 v = *(const float4*)(rowp + base + 4 * t);
    uint4 k;
    k.x = key_of(v.x); k.y = key_of(v.y); k.z = key_of(v.z); k.w = key_of(v.w);
    lmax = max(max(lmax, max(k.x, k.y)), max(k.z, k.w));
    *(uint4*)&keys[base + 4 * t] = k;
  }
#pragma unroll
  for (int off = 32; off > 0; off >>= 1) {
    const unsigned o = __shfl_xor(lmax, off);
    lmax = max(lmax, o);
  }
  if (lane == 0) wred[wv] = lmax;
  __syncthreads();
  const float m = key_to_float(max(max(wred[0], wred[1]), max(wred[2], wred[3])));

  unsigned prefix = 0u, maskHi = 0u, needK = KTOP, tieC = 0u;
#pragma unroll
  for (int pass = 0; pass < 4; ++pass) {
    const int shift = 24 - 8 * pass;
    hist[t] = 0u;
    __syncthreads();
    for (int i = t; i < Ss; i += 256) {
      const unsigned k = keys[i];
      if ((k & maskHi) == prefix) atomicAdd(&hist[(k >> shift) & 255u], 1u);
    }
    __syncthreads();
    const unsigned h = hist[t];
    unsigned s = h;
#pragma unroll
    for (int off = 1; off < 64; off <<= 1) {
      const unsigned v = __shfl_down(s, off);
      if (lane + off < 64) s += v;
    }
    if (lane == 0) wred[wv] = s;
    __syncthreads();
    unsigned stot = s;
    for (int w2 = wv + 1; w2 < 4; ++w2) stot += wred[w2];
    if (h > 0u && stot >= needK && stot - h < needK) {
      sBin = (unsigned)t;
      sNeedK = needK - (stot - h);
      sTie = h;
    }
    __syncthreads();
    prefix |= sBin << shift;
    needK = sNeedK;
    tieC  = sTie;
    maskHi |= 0xFFu << shift;
    __syncthreads();
  }
  const unsigned T = prefix;

  if (tieC != needK) {
    if (t == 0) {
      unsigned taken = 0u;
      for (int i = 0; i < Ss; ++i)
        if (keys[i] == T) { if (taken < needK) ++taken; else keys[i] = 0u; }
    }
    __syncthreads();
  }

  const float eT = __expf(key_to_float(T) - m);
  float lz = 0.f;
  for (int i = t; i < Ss; i += 256) {
    const unsigned k = keys[i];
    if (k > T) lz += __expf(key_to_float(k) - m);
  }
#pragma unroll
  for (int off = 32; off > 0; off >>= 1) lz += __shfl_xor(lz, off);
  if (lane == 0) fred[wv] = lz;
  __syncthreads();
  const float Zi  = 1.0f / (fred[0] + fred[1] + fred[2] + fred[3] + (float)needK * eT);
  const float eTZ = eT * Zi;

#pragma unroll
  for (int base = 0; base < Ss; base += 1024) {
    const int i0 = base + 4 * t;
    float4 w;
    float* wp = &w.x;
#pragma unroll
    for (int j = 0; j < 4; ++j) {
      const unsigned k = keys[i0 + j];
      wp[j] = (k > T) ? __expf(key_to_float(k) - m) * Zi : ((k == T) ? eTZ : 0.f);
    }
    *(float4*)(rowp + i0) = w;
  }
}

}  // namespace

extern "C" void kernel_launch(void* const* d_in, const int* in_sizes, int n_in,
                              void* d_out_v, int out_size, void* d_ws, size_t ws_size,
                              hipStream_t stream)
{
  const float* query = (const float*)d_in[0];
  const float* key   = (const float*)d_in[1];
  const float* value = (const float*)d_in[2];
  const float* Wq = (const float*)d_in[3];  const float* bq = (const float*)d_in[4];
  const float* Wk = (const float*)d_in[5];  const float* bk = (const float*)d_in[6];
  const float* Wv = (const float*)d_in[7];  const float* bv = (const float*)d_in[8];
  const float* Wo = (const float*)d_in[9];  const float* bo = (const float*)d_in[10];

  float* d_out = (float*)d_out_v;
  float* outp  = d_out;                              // [B,S,D] f32
  float* wts   = d_out + (size_t)Bb * Ss * Dd;       // [B,H,S,S] f32

  const size_t PROJ = (size_t)MROWS * Dd;            // 4096*1024
  float*  ws    = (float*)d_ws;
  float*  Q     = ws;                                // f32 [BH][S][DK]
  float*  Kw    = Q + PROJ;                          // f32 [BH][S][DK]
  ushort* vbf   = (ushort*)(Kw + PROJ);              // bf16 value [4096][1024]
  ushort* WvT   = vbf + PROJ;                        // bf16 Wv^T [1024][1024]
  ushort* WoT   = WvT + (size_t)Dd * Dd;             // bf16 Wo^T [1024][1024]
  ushort* Vt    = WoT + (size_t)Dd * Dd;             // bf16 V^T [16][128][2048]
  ushort* attnb = Vt + (size_t)BH * DKk * Ss;        // bf16 attn [4096][1024]

  const dim3 blk(256);

  // conversions
  conv_bf16<<<dim3((int)(PROJ / 1024)), blk, 0, stream>>>(value, vbf, (int)PROJ);
  transpose_bf16<<<dim3(32, 32), blk, 0, stream>>>(Wv, WvT);
  transpose_bf16<<<dim3(32, 32), blk, 0, stream>>>(Wo, WoT);

  // Q/K projections (f32, precision-critical for top-k selection)
  const dim3 gproj(Dd / 64, MROWS / 64);
  gemm_nn<1><<<gproj, blk, 0, stream>>>(query, Wq, bq, Q,  Dd, Dd);
  gemm_nn<1><<<gproj, blk, 0, stream>>>(key,   Wk, bk, Kw, Dd, Dd);

  // V projection (bf16 MFMA) -> V^T layout
  mfma_nt<1><<<dim3(Dd / 128, MROWS / 128, 1), blk, 0, stream>>>(
      vbf, WvT, bv, Vt, MROWS, Dd, Dd);

  // scores (f32) -> weights region of d_out
  const dim3 gsc(Ss / 64, Ss / 64, BH);
  scores_nt<<<gsc, blk, 0, stream>>>(Q, Kw, wts);

  // exact top-512 + softmax, in place
  topk_softmax<<<dim3(BH * Ss), blk, 0, stream>>>(wts);

  // PV (bf16 MFMA, stages f32 weights with inline conversion)
  mfma_nt<2><<<dim3(1, Ss / 128, BH), blk, 0, stream>>>(
      wts, Vt, nullptr, attnb, Ss, DKk, Ss);

  // output projection (bf16 MFMA, f32 out)
  mfma_nt<0><<<dim3(Dd / 128, MROWS / 128, 1), blk, 0, stream>>>(
      attnb, WoT, bo, outp, MROWS, Dd, Dd);
}

// Round 5
// 581.359 us; speedup vs baseline: 3.8615x; 1.4187x over previous
//
#include <hip/hip_runtime.h>
#include <hip/hip_bf16.h>
#include <math.h>

namespace {

constexpr int Bb   = 2;
constexpr int Ss   = 2048;
constexpr int Dd   = 1024;
constexpr int Hh   = 8;
constexpr int DKk  = 128;
constexpr int KTOP = 512;
constexpr int BH    = Bb * Hh;   // 16
constexpr int MROWS = Bb * Ss;   // 4096
constexpr float SCALE = 0.08838834764831845f;  // 1/sqrt(128)

typedef __attribute__((ext_vector_type(8))) short short8t;  // 8 bf16 = 16 B
typedef __attribute__((ext_vector_type(4))) short short4t;  // 4 bf16 = 8 B
typedef __attribute__((ext_vector_type(4))) float f32x4;

__device__ inline ushort f2bf(float x) {  // f32 -> bf16 RNE
  const unsigned u = __float_as_uint(x);
  return (ushort)((u + 0x7FFFu + ((u >> 16) & 1u)) >> 16);
}
__device__ inline float bf2f(ushort h) {
  return __uint_as_float(((unsigned)h) << 16);
}
struct HL { short h, l; };
// split x into hi + lo bf16 (hi = RNE(x), lo = RNE(x - hi))
__device__ inline HL split1(float x) {
  HL r;
  const ushort hu = f2bf(x);
  r.h = (short)hu;
  r.l = (short)f2bf(x - bf2f(hu));
  return r;
}

// ---------------------------------------------------------------------------
// Split-bf16 MFMA NT GEMM: C = A @ Bt^T computed as Ah·Bh + Ah·Bl + Al·Bh
// 128x128 tile, BK=32, 4 waves, 16x16x32 bf16 MFMA (~f32 precision).
// MODE 0: proj   — A f32 [M x K] (raw input), Bt pre-split hi/lo bf16 [N x K],
//                  +bias, out f32 scatter to [B,H,S,DK] layout
// MODE 1: scores — A,Bt f32 [z][S][DK] (Q,K), out f32 [z][S][S] * SCALE
// ---------------------------------------------------------------------------
template <int MODE>
__global__ __launch_bounds__(256) void mfma_split_nt(
    const float* __restrict__ Afp, const float* __restrict__ Bfp,
    const ushort* __restrict__ Bth, const ushort* __restrict__ Btl,
    const float* __restrict__ bias, float* __restrict__ Cout,
    int M, int N, int K)
{
  __shared__ ushort Ah[128 * 32];  // 8 KB each
  __shared__ ushort Al[128 * 32];
  __shared__ ushort Bh[128 * 32];
  __shared__ ushort Bl[128 * 32];
  const int t  = threadIdx.x;
  const int z  = blockIdx.z;
  const int n0 = blockIdx.x * 128;
  const int m0 = blockIdx.y * 128;
  const int l  = t & 63, wv = t >> 6;
  const int wr = wv >> 1, wc = wv & 1;     // wave's 64x64 quadrant
  const int lrow = l & 15, lhi = l >> 4;

  const float* Af = (MODE == 1) ? Afp + (size_t)z * Ss * DKk : Afp;
  const float* Bf = (MODE == 1) ? Bfp + (size_t)z * Ss * DKk : nullptr;

  f32x4 acc[4][4] = {};

  for (int kt = 0; kt < K; kt += 32) {
#pragma unroll
    for (int p = 0; p < 2; ++p) {
      const int li = p * 256 + t, row = li >> 2, g = li & 3;
      const int sw = row * 32 + ((g ^ (row & 3)) << 3);
      {  // A: f32 -> hi/lo
        const float* src = Af + (size_t)(m0 + row) * K + kt + g * 8;
        const float4 v0 = *(const float4*)src;
        const float4 v1 = *(const float4*)(src + 4);
        short8t h, lo;
        HL r;
        r = split1(v0.x); h[0] = r.h; lo[0] = r.l;
        r = split1(v0.y); h[1] = r.h; lo[1] = r.l;
        r = split1(v0.z); h[2] = r.h; lo[2] = r.l;
        r = split1(v0.w); h[3] = r.h; lo[3] = r.l;
        r = split1(v1.x); h[4] = r.h; lo[4] = r.l;
        r = split1(v1.y); h[5] = r.h; lo[5] = r.l;
        r = split1(v1.z); h[6] = r.h; lo[6] = r.l;
        r = split1(v1.w); h[7] = r.h; lo[7] = r.l;
        *(short8t*)&Ah[sw] = h;
        *(short8t*)&Al[sw] = lo;
      }
      if constexpr (MODE == 1) {
        const float* src = Bf + (size_t)(n0 + row) * K + kt + g * 8;
        const float4 v0 = *(const float4*)src;
        const float4 v1 = *(const float4*)(src + 4);
        short8t h, lo;
        HL r;
        r = split1(v0.x); h[0] = r.h; lo[0] = r.l;
        r = split1(v0.y); h[1] = r.h; lo[1] = r.l;
        r = split1(v0.z); h[2] = r.h; lo[2] = r.l;
        r = split1(v0.w); h[3] = r.h; lo[3] = r.l;
        r = split1(v1.x); h[4] = r.h; lo[4] = r.l;
        r = split1(v1.y); h[5] = r.h; lo[5] = r.l;
        r = split1(v1.z); h[6] = r.h; lo[6] = r.l;
        r = split1(v1.w); h[7] = r.h; lo[7] = r.l;
        *(short8t*)&Bh[sw] = h;
        *(short8t*)&Bl[sw] = lo;
      } else {
        const size_t off = (size_t)(n0 + row) * K + kt + g * 8;
        *(short8t*)&Bh[sw] = *(const short8t*)(Bth + off);
        *(short8t*)&Bl[sw] = *(const short8t*)(Btl + off);
      }
    }
    __syncthreads();

    short8t ah[4], al[4], bh[4], bl[4];
#pragma unroll
    for (int i = 0; i < 4; ++i) {
      const int row = wr * 64 + i * 16 + lrow;
      const int idx = row * 32 + ((lhi ^ (row & 3)) << 3);
      ah[i] = *(const short8t*)&Ah[idx];
      al[i] = *(const short8t*)&Al[idx];
    }
#pragma unroll
    for (int j = 0; j < 4; ++j) {
      const int row = wc * 64 + j * 16 + lrow;
      const int idx = row * 32 + ((lhi ^ (row & 3)) << 3);
      bh[j] = *(const short8t*)&Bh[idx];
      bl[j] = *(const short8t*)&Bl[idx];
    }
#pragma unroll
    for (int i = 0; i < 4; ++i)
#pragma unroll
      for (int j = 0; j < 4; ++j) {
        acc[i][j] = __builtin_amdgcn_mfma_f32_16x16x32_bf16(ah[i], bh[j], acc[i][j], 0, 0, 0);
        acc[i][j] = __builtin_amdgcn_mfma_f32_16x16x32_bf16(ah[i], bl[j], acc[i][j], 0, 0, 0);
        acc[i][j] = __builtin_amdgcn_mfma_f32_16x16x32_bf16(al[i], bh[j], acc[i][j], 0, 0, 0);
      }
    __syncthreads();
  }

  // epilogue: C/D layout col=lane&15, row=(lane>>4)*4+reg
#pragma unroll
  for (int i = 0; i < 4; ++i) {
#pragma unroll
    for (int j = 0; j < 4; ++j) {
      const int nn = n0 + wc * 64 + j * 16 + lrow;
#pragma unroll
      for (int r = 0; r < 4; ++r) {
        const int mm = m0 + wr * 64 + i * 16 + lhi * 4 + r;
        if constexpr (MODE == 0) {
          const float v = acc[i][j][r] + bias[nn];
          const int bb = mm >> 11, s = mm & (Ss - 1);
          const int hh = nn >> 7,  dk = nn & (DKk - 1);
          Cout[(((size_t)(bb * Hh + hh)) * Ss + s) * DKk + dk] = v;
        } else {
          Cout[(size_t)z * Ss * Ss + (size_t)mm * Ss + nn] = acc[i][j][r] * SCALE;
        }
      }
    }
  }
}

// ---------------------------------------------------------------------------
// bf16 MFMA NT GEMM (plain): C[M x N] = A[M x K] @ Bt[N x K]^T  (+bias)
// MODE 0: o_proj — A bf16, out f32 row-major, +bias
// MODE 1: v_proj — A bf16, out bf16 scatter Vt[bh][dk][s], +bias
// MODE 2: pv     — A f32 (weights, batched z=bh), out bf16 attn[B,S,D]
// ---------------------------------------------------------------------------
template <int MODE>
__global__ __launch_bounds__(256) void mfma_nt(
    const void* __restrict__ Ain, const ushort* __restrict__ BtAll,
    const float* __restrict__ bias, void* __restrict__ Cout,
    int M, int N, int K)
{
  __shared__ ushort As[128 * 64];  // 16 KB
  __shared__ ushort Bs[128 * 64];  // 16 KB
  const int t  = threadIdx.x;
  const int z  = blockIdx.z;
  const int n0 = blockIdx.x * 128;
  const int m0 = blockIdx.y * 128;
  const int l  = t & 63, wv = t >> 6;
  const int wr = wv >> 1, wc = wv & 1;
  const int lrow = l & 15, lhi = l >> 4;

  const float*  Af = (MODE == 2) ? ((const float*)Ain) + (size_t)z * Ss * Ss : nullptr;
  const ushort* Ab = (MODE == 2) ? nullptr : (const ushort*)Ain;
  const ushort* Bt = (MODE == 2) ? BtAll + (size_t)z * DKk * Ss : BtAll;

  f32x4 acc[4][4] = {};

  for (int kt = 0; kt < K; kt += 64) {
#pragma unroll
    for (int p = 0; p < 4; ++p) {
      const int li = p * 256 + t, row = li >> 3, g = li & 7;
      const int sw = row * 64 + ((g ^ (row & 7)) << 3);
      short8t sa;
      if constexpr (MODE == 2) {
        const float* src = Af + (size_t)(m0 + row) * K + kt + g * 8;
        const float4 v0 = *(const float4*)src;
        const float4 v1 = *(const float4*)(src + 4);
        sa[0] = (short)f2bf(v0.x); sa[1] = (short)f2bf(v0.y);
        sa[2] = (short)f2bf(v0.z); sa[3] = (short)f2bf(v0.w);
        sa[4] = (short)f2bf(v1.x); sa[5] = (short)f2bf(v1.y);
        sa[6] = (short)f2bf(v1.z); sa[7] = (short)f2bf(v1.w);
      } else {
        sa = *(const short8t*)(Ab + (size_t)(m0 + row) * K + kt + g * 8);
      }
      *(short8t*)&As[sw] = sa;
      const short8t sb = *(const short8t*)(Bt + (size_t)(n0 + row) * K + kt + g * 8);
      *(short8t*)&Bs[sw] = sb;
    }
    __syncthreads();

#pragma unroll
    for (int kk = 0; kk < 2; ++kk) {
      short8t a[4], b[4];
      const int g = kk * 4 + lhi;
#pragma unroll
      for (int i = 0; i < 4; ++i) {
        const int row = wr * 64 + i * 16 + lrow;
        a[i] = *(const short8t*)&As[row * 64 + ((g ^ (row & 7)) << 3)];
      }
#pragma unroll
      for (int j = 0; j < 4; ++j) {
        const int row = wc * 64 + j * 16 + lrow;
        b[j] = *(const short8t*)&Bs[row * 64 + ((g ^ (row & 7)) << 3)];
      }
#pragma unroll
      for (int i = 0; i < 4; ++i)
#pragma unroll
        for (int j = 0; j < 4; ++j)
          acc[i][j] = __builtin_amdgcn_mfma_f32_16x16x32_bf16(a[i], b[j], acc[i][j], 0, 0, 0);
    }
    __syncthreads();
  }

#pragma unroll
  for (int i = 0; i < 4; ++i) {
#pragma unroll
    for (int j = 0; j < 4; ++j) {
      const int nn = n0 + wc * 64 + j * 16 + lrow;
#pragma unroll
      for (int r = 0; r < 4; ++r) {
        const int mm = m0 + wr * 64 + i * 16 + lhi * 4 + r;
        const float v = acc[i][j][r];
        if constexpr (MODE == 0) {
          ((float*)Cout)[(size_t)mm * N + nn] = v + bias[nn];
        } else if constexpr (MODE == 1) {
          const int bb = mm >> 11, s = mm & (Ss - 1);
          const int hh = nn >> 7,  dk = nn & (DKk - 1);
          ((ushort*)Cout)[((size_t)((bb * Hh + hh) * DKk + dk)) * Ss + s] =
              f2bf(v + bias[nn]);
        } else {
          const int bb = z >> 3, hh = z & 7;
          ((ushort*)Cout)[((size_t)(bb * Ss + mm)) * Dd + hh * DKk + nn] = f2bf(v);
        }
      }
    }
  }
}

// ---------------------------------------------------------------------------
// f32 -> bf16 elementwise conversion
// ---------------------------------------------------------------------------
__global__ __launch_bounds__(256) void conv_bf16(
    const float* __restrict__ in, ushort* __restrict__ out, int n)
{
  const int i = (blockIdx.x * 256 + threadIdx.x) * 4;
  if (i < n) {
    const float4 v = *(const float4*)(in + i);
    short4t o;
    o[0] = (short)f2bf(v.x); o[1] = (short)f2bf(v.y);
    o[2] = (short)f2bf(v.z); o[3] = (short)f2bf(v.w);
    *(short4t*)(out + i) = o;
  }
}

// ---------------------------------------------------------------------------
// W[1024][1024] f32 -> Wt bf16 (transposed), plain
// ---------------------------------------------------------------------------
__global__ __launch_bounds__(256) void transpose_bf16(
    const float* __restrict__ W, ushort* __restrict__ Wt)
{
  __shared__ float tile[32][33];
  const int t  = threadIdx.x;
  const int c0 = blockIdx.x * 32, r0 = blockIdx.y * 32;
  const int lr = t >> 3, lc4 = (t & 7) * 4;
  const float4 v = *(const float4*)(W + (size_t)(r0 + lr) * Dd + c0 + lc4);
  tile[lr][lc4 + 0] = v.x; tile[lr][lc4 + 1] = v.y;
  tile[lr][lc4 + 2] = v.z; tile[lr][lc4 + 3] = v.w;
  __syncthreads();
  const int oc = t >> 3, or4 = (t & 7) * 4;
  short4t o;
  o[0] = (short)f2bf(tile[or4 + 0][oc]);
  o[1] = (short)f2bf(tile[or4 + 1][oc]);
  o[2] = (short)f2bf(tile[or4 + 2][oc]);
  o[3] = (short)f2bf(tile[or4 + 3][oc]);
  *(short4t*)(Wt + (size_t)(c0 + oc) * Dd + r0 + or4) = o;
}

// ---------------------------------------------------------------------------
// W[1024][1024] f32 -> transposed hi/lo bf16 split
// ---------------------------------------------------------------------------
__global__ __launch_bounds__(256) void transpose_split(
    const float* __restrict__ W, ushort* __restrict__ Th, ushort* __restrict__ Tl)
{
  __shared__ float tile[32][33];
  const int t  = threadIdx.x;
  const int c0 = blockIdx.x * 32, r0 = blockIdx.y * 32;
  const int lr = t >> 3, lc4 = (t & 7) * 4;
  const float4 v = *(const float4*)(W + (size_t)(r0 + lr) * Dd + c0 + lc4);
  tile[lr][lc4 + 0] = v.x; tile[lr][lc4 + 1] = v.y;
  tile[lr][lc4 + 2] = v.z; tile[lr][lc4 + 3] = v.w;
  __syncthreads();
  const int oc = t >> 3, or4 = (t & 7) * 4;
  short4t oh, ol;
  HL r;
  r = split1(tile[or4 + 0][oc]); oh[0] = r.h; ol[0] = r.l;
  r = split1(tile[or4 + 1][oc]); oh[1] = r.h; ol[1] = r.l;
  r = split1(tile[or4 + 2][oc]); oh[2] = r.h; ol[2] = r.l;
  r = split1(tile[or4 + 3][oc]); oh[3] = r.h; ol[3] = r.l;
  *(short4t*)(Th + (size_t)(c0 + oc) * Dd + r0 + or4) = oh;
  *(short4t*)(Tl + (size_t)(c0 + oc) * Dd + r0 + or4) = ol;
}

__device__ inline unsigned key_of(float v) {
  const unsigned u = __float_as_uint(v);
  return (u & 0x80000000u) ? ~u : (u | 0x80000000u);
}
__device__ inline float key_to_float(unsigned k) {
  const unsigned u = (k & 0x80000000u) ? (k & 0x7FFFFFFFu) : ~k;
  return __uint_as_float(u);
}

// ---------------------------------------------------------------------------
// Per-row exact top-512 (radix-256 select) + softmax, in place.
// ---------------------------------------------------------------------------
__global__ __launch_bounds__(256) void topk_softmax(float* __restrict__ wts)
{
  __shared__ unsigned keys[Ss];
  __shared__ unsigned hist[256];
  __shared__ unsigned wred[4];
  __shared__ float    fred[4];
  __shared__ unsigned sBin, sNeedK, sTie;

  const int t    = threadIdx.x;
  const int lane = t & 63;
  const int wv   = t >> 6;
  float* rowp = wts + (size_t)blockIdx.x * Ss;

  unsigned lmax = 0u;
#pragma unroll
  for (int base = 0; base < Ss; base += 1024) {
    const float4 v = *(const float4*)(rowp + base + 4 * t);
    uint4 k;
    k.x = key_of(v.x); k.y = key_of(v.y); k.z = key_of(v.z); k.w = key_of(v.w);
    lmax = max(max(lmax, max(k.x, k.y)), max(k.z, k.w));
    *(uint4*)&keys[base + 4 * t] = k;
  }
#pragma unroll
  for (int off = 32; off > 0; off >>= 1) {
    const unsigned o = __shfl_xor(lmax, off);
    lmax = max(lmax, o);
  }
  if (lane == 0) wred[wv] = lmax;
  __syncthreads();
  const float m = key_to_float(max(max(wred[0], wred[1]), max(wred[2], wred[3])));

  unsigned prefix = 0u, maskHi = 0u, needK = KTOP, tieC = 0u;
#pragma unroll
  for (int pass = 0; pass < 4; ++pass) {
    const int shift = 24 - 8 * pass;
    hist[t] = 0u;
    __syncthreads();
    for (int i = t; i < Ss; i += 256) {
      const unsigned k = keys[i];
      if ((k & maskHi) == prefix) atomicAdd(&hist[(k >> shift) & 255u], 1u);
    }
    __syncthreads();
    const unsigned h = hist[t];
    unsigned s = h;
#pragma unroll
    for (int off = 1; off < 64; off <<= 1) {
      const unsigned v = __shfl_down(s, off);
      if (lane + off < 64) s += v;
    }
    if (lane == 0) wred[wv] = s;
    __syncthreads();
    unsigned stot = s;
    for (int w2 = wv + 1; w2 < 4; ++w2) stot += wred[w2];
    if (h > 0u && stot >= needK && stot - h < needK) {
      sBin = (unsigned)t;
      sNeedK = needK - (stot - h);
      sTie = h;
    }
    __syncthreads();
    prefix |= sBin << shift;
    needK = sNeedK;
    tieC  = sTie;
    maskHi |= 0xFFu << shift;
    __syncthreads();
  }
  const unsigned T = prefix;

  if (tieC != needK) {
    if (t == 0) {
      unsigned taken = 0u;
      for (int i = 0; i < Ss; ++i)
        if (keys[i] == T) { if (taken < needK) ++taken; else keys[i] = 0u; }
    }
    __syncthreads();
  }

  const float eT = __expf(key_to_float(T) - m);
  float lz = 0.f;
  for (int i = t; i < Ss; i += 256) {
    const unsigned k = keys[i];
    if (k > T) lz += __expf(key_to_float(k) - m);
  }
#pragma unroll
  for (int off = 32; off > 0; off >>= 1) lz += __shfl_xor(lz, off);
  if (lane == 0) fred[wv] = lz;
  __syncthreads();
  const float Zi  = 1.0f / (fred[0] + fred[1] + fred[2] + fred[3] + (float)needK * eT);
  const float eTZ = eT * Zi;

#pragma unroll
  for (int base = 0; base < Ss; base += 1024) {
    const int i0 = base + 4 * t;
    float4 w;
    float* wp = &w.x;
#pragma unroll
    for (int j = 0; j < 4; ++j) {
      const unsigned k = keys[i0 + j];
      wp[j] = (k > T) ? __expf(key_to_float(k) - m) * Zi : ((k == T) ? eTZ : 0.f);
    }
    *(float4*)(rowp + i0) = w;
  }
}

}  // namespace

extern "C" void kernel_launch(void* const* d_in, const int* in_sizes, int n_in,
                              void* d_out_v, int out_size, void* d_ws, size_t ws_size,
                              hipStream_t stream)
{
  const float* query = (const float*)d_in[0];
  const float* key   = (const float*)d_in[1];
  const float* value = (const float*)d_in[2];
  const float* Wq = (const float*)d_in[3];  const float* bq = (const float*)d_in[4];
  const float* Wk = (const float*)d_in[5];  const float* bk = (const float*)d_in[6];
  const float* Wv = (const float*)d_in[7];  const float* bv = (const float*)d_in[8];
  const float* Wo = (const float*)d_in[9];  const float* bo = (const float*)d_in[10];

  float* d_out = (float*)d_out_v;
  float* outp  = d_out;                              // [B,S,D] f32
  float* wts   = d_out + (size_t)Bb * Ss * Dd;       // [B,H,S,S] f32

  const size_t PROJ = (size_t)MROWS * Dd;            // 4M elements
  const size_t DD2  = (size_t)Dd * Dd;               // 1M elements

  float*  ws    = (float*)d_ws;
  float*  Q     = ws;                                // f32 [BH][S][DK]  16 MB
  float*  Kw    = Q + PROJ;                          // f32 [BH][S][DK]  16 MB
  ushort* r3    = (ushort*)(Kw + PROJ);              // 8 MB region
  ushort* WqTh  = r3;                                //   Wq^T hi
  ushort* WqTl  = r3 + DD2;                          //   Wq^T lo
  ushort* WkTh  = r3 + 2 * DD2;                      //   Wk^T hi
  ushort* WkTl  = r3 + 3 * DD2;                      //   Wk^T lo
  ushort* vbf   = r3;                                //   (aliases after K proj)
  ushort* WvT   = r3 + 4 * DD2;                      // 2 MB
  ushort* WoT   = WvT + DD2;                         // 2 MB
  ushort* Vt    = WoT + DD2;                         // bf16 V^T [16][128][2048] 8 MB
  ushort* attnb = Vt + (size_t)BH * DKk * Ss;        // bf16 attn [4096][1024]  8 MB

  const dim3 blk(256);

  // weight prep
  transpose_split<<<dim3(32, 32), blk, 0, stream>>>(Wq, WqTh, WqTl);
  transpose_split<<<dim3(32, 32), blk, 0, stream>>>(Wk, WkTh, WkTl);
  transpose_bf16<<<dim3(32, 32), blk, 0, stream>>>(Wv, WvT);
  transpose_bf16<<<dim3(32, 32), blk, 0, stream>>>(Wo, WoT);

  // Q/K projections: split-bf16 MFMA (~f32 precision), out f32 [BH][S][DK]
  const dim3 gp(Dd / 128, MROWS / 128, 1);
  mfma_split_nt<0><<<gp, blk, 0, stream>>>(query, nullptr, WqTh, WqTl, bq, Q,
                                           MROWS, Dd, Dd);
  mfma_split_nt<0><<<gp, blk, 0, stream>>>(key, nullptr, WkTh, WkTl, bk, Kw,
                                           MROWS, Dd, Dd);

  // value -> bf16 (into the now-dead WqT/WkT region)
  conv_bf16<<<dim3((int)(PROJ / 1024)), blk, 0, stream>>>(value, vbf, (int)PROJ);

  // V projection (plain bf16 MFMA) -> V^T layout
  mfma_nt<1><<<dim3(Dd / 128, MROWS / 128, 1), blk, 0, stream>>>(
      vbf, WvT, bv, Vt, MROWS, Dd, Dd);

  // scores: split-bf16 MFMA, inline split of Q and K, out f32 * SCALE
  mfma_split_nt<1><<<dim3(Ss / 128, Ss / 128, BH), blk, 0, stream>>>(
      Q, Kw, nullptr, nullptr, nullptr, wts, Ss, Ss, DKk);

  // exact top-512 + softmax, in place
  topk_softmax<<<dim3(BH * Ss), blk, 0, stream>>>(wts);

  // PV (bf16 MFMA, stages f32 weights with inline conversion)
  mfma_nt<2><<<dim3(1, Ss / 128, BH), blk, 0, stream>>>(
      wts, Vt, nullptr, attnb, Ss, DKk, Ss);

  // output projection (bf16 MFMA, f32 out)
  mfma_nt<0><<<dim3(Dd / 128, MROWS / 128, 1), blk, 0, stream>>>(
      attnb, WoT, bo, outp, MROWS, Dd, Dd);
}

// Round 6
// 567.276 us; speedup vs baseline: 3.9573x; 1.0248x over previous
//
#include <hip/hip_runtime.h>
#include <hip/hip_bf16.h>
#include <math.h>

namespace {

constexpr int Bb   = 2;
constexpr int Ss   = 2048;
constexpr int Dd   = 1024;
constexpr int Hh   = 8;
constexpr int DKk  = 128;
constexpr int KTOP = 512;
constexpr int BH    = Bb * Hh;   // 16
constexpr int MROWS = Bb * Ss;   // 4096
constexpr float SCALE = 0.08838834764831845f;  // 1/sqrt(128)

typedef __attribute__((ext_vector_type(8))) short short8t;  // 8 bf16 = 16 B
typedef __attribute__((ext_vector_type(4))) short short4t;  // 4 bf16 = 8 B
typedef __attribute__((ext_vector_type(4))) float f32x4;

__device__ inline ushort f2bf(float x) {  // f32 -> bf16 RNE
  const unsigned u = __float_as_uint(x);
  return (ushort)((u + 0x7FFFu + ((u >> 16) & 1u)) >> 16);
}
__device__ inline float bf2f(ushort h) {
  return __uint_as_float(((unsigned)h) << 16);
}
struct HL { short h, l; };
// split x into hi + lo bf16 (hi = RNE(x), lo = RNE(x - hi))
__device__ inline HL split1(float x) {
  HL r;
  const ushort hu = f2bf(x);
  r.h = (short)hu;
  r.l = (short)f2bf(x - bf2f(hu));
  return r;
}

// ---------------------------------------------------------------------------
// Split-bf16 MFMA NT GEMM: C = A @ Bt^T computed as Ah·Bh + Ah·Bl + Al·Bh
// 128x128 tile, BK=32, 4 waves, 16x16x32 bf16 MFMA (~f32 precision).
// MODE 0: proj   — A f32 [M x K] (raw input), Bt pre-split hi/lo bf16 [N x K],
//                  +bias, out f32 scatter to [B,H,S,DK] layout
// MODE 1: scores — A,Bt f32 [z][S][DK] (Q,K), out f32 [z][S][S] * SCALE
// ---------------------------------------------------------------------------
template <int MODE>
__global__ __launch_bounds__(256) void mfma_split_nt(
    const float* __restrict__ Afp, const float* __restrict__ Bfp,
    const ushort* __restrict__ Bth, const ushort* __restrict__ Btl,
    const float* __restrict__ bias, float* __restrict__ Cout,
    int M, int N, int K)
{
  __shared__ ushort Ah[128 * 32];  // 8 KB each
  __shared__ ushort Al[128 * 32];
  __shared__ ushort Bh[128 * 32];
  __shared__ ushort Bl[128 * 32];
  const int t  = threadIdx.x;
  const int z  = blockIdx.z;
  const int n0 = blockIdx.x * 128;
  const int m0 = blockIdx.y * 128;
  const int l  = t & 63, wv = t >> 6;
  const int wr = wv >> 1, wc = wv & 1;     // wave's 64x64 quadrant
  const int lrow = l & 15, lhi = l >> 4;

  const float* Af = (MODE == 1) ? Afp + (size_t)z * Ss * DKk : Afp;
  const float* Bf = (MODE == 1) ? Bfp + (size_t)z * Ss * DKk : nullptr;

  f32x4 acc[4][4] = {};

  for (int kt = 0; kt < K; kt += 32) {
#pragma unroll
    for (int p = 0; p < 2; ++p) {
      const int li = p * 256 + t, row = li >> 2, g = li & 3;
      const int sw = row * 32 + ((g ^ (row & 3)) << 3);
      {  // A: f32 -> hi/lo
        const float* src = Af + (size_t)(m0 + row) * K + kt + g * 8;
        const float4 v0 = *(const float4*)src;
        const float4 v1 = *(const float4*)(src + 4);
        short8t h, lo;
        HL r;
        r = split1(v0.x); h[0] = r.h; lo[0] = r.l;
        r = split1(v0.y); h[1] = r.h; lo[1] = r.l;
        r = split1(v0.z); h[2] = r.h; lo[2] = r.l;
        r = split1(v0.w); h[3] = r.h; lo[3] = r.l;
        r = split1(v1.x); h[4] = r.h; lo[4] = r.l;
        r = split1(v1.y); h[5] = r.h; lo[5] = r.l;
        r = split1(v1.z); h[6] = r.h; lo[6] = r.l;
        r = split1(v1.w); h[7] = r.h; lo[7] = r.l;
        *(short8t*)&Ah[sw] = h;
        *(short8t*)&Al[sw] = lo;
      }
      if constexpr (MODE == 1) {
        const float* src = Bf + (size_t)(n0 + row) * K + kt + g * 8;
        const float4 v0 = *(const float4*)src;
        const float4 v1 = *(const float4*)(src + 4);
        short8t h, lo;
        HL r;
        r = split1(v0.x); h[0] = r.h; lo[0] = r.l;
        r = split1(v0.y); h[1] = r.h; lo[1] = r.l;
        r = split1(v0.z); h[2] = r.h; lo[2] = r.l;
        r = split1(v0.w); h[3] = r.h; lo[3] = r.l;
        r = split1(v1.x); h[4] = r.h; lo[4] = r.l;
        r = split1(v1.y); h[5] = r.h; lo[5] = r.l;
        r = split1(v1.z); h[6] = r.h; lo[6] = r.l;
        r = split1(v1.w); h[7] = r.h; lo[7] = r.l;
        *(short8t*)&Bh[sw] = h;
        *(short8t*)&Bl[sw] = lo;
      } else {
        const size_t off = (size_t)(n0 + row) * K + kt + g * 8;
        *(short8t*)&Bh[sw] = *(const short8t*)(Bth + off);
        *(short8t*)&Bl[sw] = *(const short8t*)(Btl + off);
      }
    }
    __syncthreads();

    short8t ah[4], al[4], bh[4], bl[4];
#pragma unroll
    for (int i = 0; i < 4; ++i) {
      const int row = wr * 64 + i * 16 + lrow;
      const int idx = row * 32 + ((lhi ^ (row & 3)) << 3);
      ah[i] = *(const short8t*)&Ah[idx];
      al[i] = *(const short8t*)&Al[idx];
    }
#pragma unroll
    for (int j = 0; j < 4; ++j) {
      const int row = wc * 64 + j * 16 + lrow;
      const int idx = row * 32 + ((lhi ^ (row & 3)) << 3);
      bh[j] = *(const short8t*)&Bh[idx];
      bl[j] = *(const short8t*)&Bl[idx];
    }
#pragma unroll
    for (int i = 0; i < 4; ++i)
#pragma unroll
      for (int j = 0; j < 4; ++j) {
        acc[i][j] = __builtin_amdgcn_mfma_f32_16x16x32_bf16(ah[i], bh[j], acc[i][j], 0, 0, 0);
        acc[i][j] = __builtin_amdgcn_mfma_f32_16x16x32_bf16(ah[i], bl[j], acc[i][j], 0, 0, 0);
        acc[i][j] = __builtin_amdgcn_mfma_f32_16x16x32_bf16(al[i], bh[j], acc[i][j], 0, 0, 0);
      }
    __syncthreads();
  }

  // epilogue: C/D layout col=lane&15, row=(lane>>4)*4+reg
#pragma unroll
  for (int i = 0; i < 4; ++i) {
#pragma unroll
    for (int j = 0; j < 4; ++j) {
      const int nn = n0 + wc * 64 + j * 16 + lrow;
#pragma unroll
      for (int r = 0; r < 4; ++r) {
        const int mm = m0 + wr * 64 + i * 16 + lhi * 4 + r;
        if constexpr (MODE == 0) {
          const float v = acc[i][j][r] + bias[nn];
          const int bb = mm >> 11, s = mm & (Ss - 1);
          const int hh = nn >> 7,  dk = nn & (DKk - 1);
          Cout[(((size_t)(bb * Hh + hh)) * Ss + s) * DKk + dk] = v;
        } else {
          Cout[(size_t)z * Ss * Ss + (size_t)mm * Ss + nn] = acc[i][j][r] * SCALE;
        }
      }
    }
  }
}

// ---------------------------------------------------------------------------
// bf16 MFMA NT GEMM (plain): C[M x N] = A[M x K] @ Bt[N x K]^T  (+bias)
// MODE 0: o_proj — A bf16, out f32 row-major, +bias
// MODE 1: v_proj — A bf16, out bf16 scatter Vt[bh][dk][s], +bias
// MODE 2: pv     — A f32 (weights, batched z=bh), out bf16 attn[B,S,D]
// ---------------------------------------------------------------------------
template <int MODE>
__global__ __launch_bounds__(256) void mfma_nt(
    const void* __restrict__ Ain, const ushort* __restrict__ BtAll,
    const float* __restrict__ bias, void* __restrict__ Cout,
    int M, int N, int K)
{
  __shared__ ushort As[128 * 64];  // 16 KB
  __shared__ ushort Bs[128 * 64];  // 16 KB
  const int t  = threadIdx.x;
  const int z  = blockIdx.z;
  const int n0 = blockIdx.x * 128;
  const int m0 = blockIdx.y * 128;
  const int l  = t & 63, wv = t >> 6;
  const int wr = wv >> 1, wc = wv & 1;
  const int lrow = l & 15, lhi = l >> 4;

  const float*  Af = (MODE == 2) ? ((const float*)Ain) + (size_t)z * Ss * Ss : nullptr;
  const ushort* Ab = (MODE == 2) ? nullptr : (const ushort*)Ain;
  const ushort* Bt = (MODE == 2) ? BtAll + (size_t)z * DKk * Ss : BtAll;

  f32x4 acc[4][4] = {};

  for (int kt = 0; kt < K; kt += 64) {
#pragma unroll
    for (int p = 0; p < 4; ++p) {
      const int li = p * 256 + t, row = li >> 3, g = li & 7;
      const int sw = row * 64 + ((g ^ (row & 7)) << 3);
      short8t sa;
      if constexpr (MODE == 2) {
        const float* src = Af + (size_t)(m0 + row) * K + kt + g * 8;
        const float4 v0 = *(const float4*)src;
        const float4 v1 = *(const float4*)(src + 4);
        sa[0] = (short)f2bf(v0.x); sa[1] = (short)f2bf(v0.y);
        sa[2] = (short)f2bf(v0.z); sa[3] = (short)f2bf(v0.w);
        sa[4] = (short)f2bf(v1.x); sa[5] = (short)f2bf(v1.y);
        sa[6] = (short)f2bf(v1.z); sa[7] = (short)f2bf(v1.w);
      } else {
        sa = *(const short8t*)(Ab + (size_t)(m0 + row) * K + kt + g * 8);
      }
      *(short8t*)&As[sw] = sa;
      const short8t sb = *(const short8t*)(Bt + (size_t)(n0 + row) * K + kt + g * 8);
      *(short8t*)&Bs[sw] = sb;
    }
    __syncthreads();

#pragma unroll
    for (int kk = 0; kk < 2; ++kk) {
      short8t a[4], b[4];
      const int g = kk * 4 + lhi;
#pragma unroll
      for (int i = 0; i < 4; ++i) {
        const int row = wr * 64 + i * 16 + lrow;
        a[i] = *(const short8t*)&As[row * 64 + ((g ^ (row & 7)) << 3)];
      }
#pragma unroll
      for (int j = 0; j < 4; ++j) {
        const int row = wc * 64 + j * 16 + lrow;
        b[j] = *(const short8t*)&Bs[row * 64 + ((g ^ (row & 7)) << 3)];
      }
#pragma unroll
      for (int i = 0; i < 4; ++i)
#pragma unroll
        for (int j = 0; j < 4; ++j)
          acc[i][j] = __builtin_amdgcn_mfma_f32_16x16x32_bf16(a[i], b[j], acc[i][j], 0, 0, 0);
    }
    __syncthreads();
  }

#pragma unroll
  for (int i = 0; i < 4; ++i) {
#pragma unroll
    for (int j = 0; j < 4; ++j) {
      const int nn = n0 + wc * 64 + j * 16 + lrow;
#pragma unroll
      for (int r = 0; r < 4; ++r) {
        const int mm = m0 + wr * 64 + i * 16 + lhi * 4 + r;
        const float v = acc[i][j][r];
        if constexpr (MODE == 0) {
          ((float*)Cout)[(size_t)mm * N + nn] = v + bias[nn];
        } else if constexpr (MODE == 1) {
          const int bb = mm >> 11, s = mm & (Ss - 1);
          const int hh = nn >> 7,  dk = nn & (DKk - 1);
          ((ushort*)Cout)[((size_t)((bb * Hh + hh) * DKk + dk)) * Ss + s] =
              f2bf(v + bias[nn]);
        } else {
          const int bb = z >> 3, hh = z & 7;
          ((ushort*)Cout)[((size_t)(bb * Ss + mm)) * Dd + hh * DKk + nn] = f2bf(v);
        }
      }
    }
  }
}

// ---------------------------------------------------------------------------
// f32 -> bf16 elementwise conversion
// ---------------------------------------------------------------------------
__global__ __launch_bounds__(256) void conv_bf16(
    const float* __restrict__ in, ushort* __restrict__ out, int n)
{
  const int i = (blockIdx.x * 256 + threadIdx.x) * 4;
  if (i < n) {
    const float4 v = *(const float4*)(in + i);
    short4t o;
    o[0] = (short)f2bf(v.x); o[1] = (short)f2bf(v.y);
    o[2] = (short)f2bf(v.z); o[3] = (short)f2bf(v.w);
    *(short4t*)(out + i) = o;
  }
}

// ---------------------------------------------------------------------------
// W[1024][1024] f32 -> Wt bf16 (transposed), plain
// ---------------------------------------------------------------------------
__global__ __launch_bounds__(256) void transpose_bf16(
    const float* __restrict__ W, ushort* __restrict__ Wt)
{
  __shared__ float tile[32][33];
  const int t  = threadIdx.x;
  const int c0 = blockIdx.x * 32, r0 = blockIdx.y * 32;
  const int lr = t >> 3, lc4 = (t & 7) * 4;
  const float4 v = *(const float4*)(W + (size_t)(r0 + lr) * Dd + c0 + lc4);
  tile[lr][lc4 + 0] = v.x; tile[lr][lc4 + 1] = v.y;
  tile[lr][lc4 + 2] = v.z; tile[lr][lc4 + 3] = v.w;
  __syncthreads();
  const int oc = t >> 3, or4 = (t & 7) * 4;
  short4t o;
  o[0] = (short)f2bf(tile[or4 + 0][oc]);
  o[1] = (short)f2bf(tile[or4 + 1][oc]);
  o[2] = (short)f2bf(tile[or4 + 2][oc]);
  o[3] = (short)f2bf(tile[or4 + 3][oc]);
  *(short4t*)(Wt + (size_t)(c0 + oc) * Dd + r0 + or4) = o;
}

// ---------------------------------------------------------------------------
// W[1024][1024] f32 -> transposed hi/lo bf16 split
// ---------------------------------------------------------------------------
__global__ __launch_bounds__(256) void transpose_split(
    const float* __restrict__ W, ushort* __restrict__ Th, ushort* __restrict__ Tl)
{
  __shared__ float tile[32][33];
  const int t  = threadIdx.x;
  const int c0 = blockIdx.x * 32, r0 = blockIdx.y * 32;
  const int lr = t >> 3, lc4 = (t & 7) * 4;
  const float4 v = *(const float4*)(W + (size_t)(r0 + lr) * Dd + c0 + lc4);
  tile[lr][lc4 + 0] = v.x; tile[lr][lc4 + 1] = v.y;
  tile[lr][lc4 + 2] = v.z; tile[lr][lc4 + 3] = v.w;
  __syncthreads();
  const int oc = t >> 3, or4 = (t & 7) * 4;
  short4t oh, ol;
  HL r;
  r = split1(tile[or4 + 0][oc]); oh[0] = r.h; ol[0] = r.l;
  r = split1(tile[or4 + 1][oc]); oh[1] = r.h; ol[1] = r.l;
  r = split1(tile[or4 + 2][oc]); oh[2] = r.h; ol[2] = r.l;
  r = split1(tile[or4 + 3][oc]); oh[3] = r.h; ol[3] = r.l;
  *(short4t*)(Th + (size_t)(c0 + oc) * Dd + r0 + or4) = oh;
  *(short4t*)(Tl + (size_t)(c0 + oc) * Dd + r0 + or4) = ol;
}

__device__ inline unsigned key_of(float v) {
  const unsigned u = __float_as_uint(v);
  return (u & 0x80000000u) ? ~u : (u | 0x80000000u);
}
__device__ inline float key_to_float(unsigned k) {
  const unsigned u = (k & 0x80000000u) ? (k & 0x7FFFFFFFu) : ~k;
  return __uint_as_float(u);
}

// ---------------------------------------------------------------------------
// Per-row exact top-512 (radix-256 select) + softmax, in place.
// v2: pass-1 histogram fused into the load loop with 8 replicated padded
// histograms (kills same-bin LDS-atomic serialization); threshold-bin
// candidates compacted so passes 2-4 sweep ~C<=512 elements, not 2048.
// One block (256 threads = 4 waves) per row.
// ---------------------------------------------------------------------------
__global__ __launch_bounds__(256) void topk_softmax(float* __restrict__ wts)
{
  __shared__ unsigned keys[Ss];        // 8 KB
  __shared__ unsigned hist8[8][257];   // 8.2 KB (padded: copies on distinct banks)
  __shared__ unsigned hist[256];       // 1 KB (passes 2-4)
  __shared__ ushort   cand[Ss];        // 4 KB worst case
  __shared__ unsigned wredA[4];        // max reduce
  __shared__ unsigned wredB[4];        // scan totals
  __shared__ float    fred[4];
  __shared__ unsigned sBin, sNeedK, sTie, sCnt;

  const int t    = threadIdx.x;
  const int lane = t & 63;
  const int wv   = t >> 6;
  const int hc   = (t >> 3) & 7;       // histogram copy (<=8-way contention)
  float* rowp = wts + (size_t)blockIdx.x * Ss;

  for (int i = t; i < 8 * 257; i += 256) ((unsigned*)hist8)[i] = 0u;
  if (t == 0) sCnt = 0u;
  __syncthreads();

  // ---- load row, build keys, fused pass-1 histogram, running max ----
  unsigned lmax = 0u;
#pragma unroll
  for (int base = 0; base < Ss; base += 1024) {
    const float4 v = *(const float4*)(rowp + base + 4 * t);
    uint4 k;
    k.x = key_of(v.x); k.y = key_of(v.y); k.z = key_of(v.z); k.w = key_of(v.w);
    lmax = max(max(lmax, max(k.x, k.y)), max(k.z, k.w));
    *(uint4*)&keys[base + 4 * t] = k;
    atomicAdd(&hist8[hc][k.x >> 24], 1u);
    atomicAdd(&hist8[hc][k.y >> 24], 1u);
    atomicAdd(&hist8[hc][k.z >> 24], 1u);
    atomicAdd(&hist8[hc][k.w >> 24], 1u);
  }
#pragma unroll
  for (int off = 32; off > 0; off >>= 1) {
    const unsigned o = __shfl_xor(lmax, off);
    lmax = max(lmax, o);
  }
  if (lane == 0) wredA[wv] = lmax;
  __syncthreads();
  const float m = key_to_float(max(max(wredA[0], wredA[1]), max(wredA[2], wredA[3])));

  // ---- pass 1 selection: suffix scan over reduced 256-bin histogram ----
  unsigned needK = KTOP;
  {
    unsigned h = 0u;
#pragma unroll
    for (int c = 0; c < 8; ++c) h += hist8[c][t];
    unsigned s = h;
#pragma unroll
    for (int off = 1; off < 64; off <<= 1) {
      const unsigned v = __shfl_down(s, off);
      if (lane + off < 64) s += v;
    }
    if (lane == 0) wredB[wv] = s;
    __syncthreads();
    unsigned stot = s;
    for (int w2 = wv + 1; w2 < 4; ++w2) stot += wredB[w2];
    if (h > 0u && stot >= needK && stot - h < needK) {
      sBin = (unsigned)t;
      sNeedK = needK - (stot - h);
      sTie = h;
    }
    __syncthreads();
  }
  const unsigned b1 = sBin;
  needK = sNeedK;
  unsigned tieC = sTie;

  // ---- compact threshold-bin candidates ----
#pragma unroll
  for (int base = 0; base < Ss; base += 1024) {
    const uint4 k = *(const uint4*)&keys[base + 4 * t];
    const int i0 = base + 4 * t;
    if ((k.x >> 24) == b1) cand[atomicAdd(&sCnt, 1u)] = (ushort)(i0 + 0);
    if ((k.y >> 24) == b1) cand[atomicAdd(&sCnt, 1u)] = (ushort)(i0 + 1);
    if ((k.z >> 24) == b1) cand[atomicAdd(&sCnt, 1u)] = (ushort)(i0 + 2);
    if ((k.w >> 24) == b1) cand[atomicAdd(&sCnt, 1u)] = (ushort)(i0 + 3);
  }
  __syncthreads();
  const unsigned C = sCnt;

  // ---- passes 2-4 over candidates only ----
  unsigned prefix = b1 << 24, maskHi = 0xFF000000u;
#pragma unroll
  for (int pass = 1; pass < 4; ++pass) {
    const int shift = 24 - 8 * pass;
    hist[t] = 0u;
    __syncthreads();
    for (unsigned i = t; i < C; i += 256) {
      const unsigned k = keys[cand[i]];
      if ((k & maskHi) == prefix) atomicAdd(&hist[(k >> shift) & 255u], 1u);
    }
    __syncthreads();
    const unsigned h = hist[t];
    unsigned s = h;
#pragma unroll
    for (int off = 1; off < 64; off <<= 1) {
      const unsigned v = __shfl_down(s, off);
      if (lane + off < 64) s += v;
    }
    if (lane == 0) wredB[wv] = s;
    __syncthreads();
    unsigned stot = s;
    for (int w2 = wv + 1; w2 < 4; ++w2) stot += wredB[w2];
    if (h > 0u && stot >= needK && stot - h < needK) {
      sBin = (unsigned)t;
      sNeedK = needK - (stot - h);
      sTie = h;
    }
    __syncthreads();
    prefix |= sBin << shift;
    needK = sNeedK;
    tieC  = sTie;
    maskHi |= 0xFFu << shift;
    __syncthreads();
  }
  const unsigned T = prefix;  // exact bits of the 512-th largest value

  // ---- rare path: duplicates of T straddle the boundary -> rank by index ----
  if (tieC != needK) {
    if (t == 0) {
      unsigned taken = 0u;
      for (int i = 0; i < Ss; ++i)
        if (keys[i] == T) { if (taken < needK) ++taken; else keys[i] = 0u; }
    }
    __syncthreads();
  }

  // ---- softmax over selected entries ----
  const float eT = __expf(key_to_float(T) - m);
  float lz = 0.f;
#pragma unroll
  for (int base = 0; base < Ss; base += 1024) {
    const uint4 k = *(const uint4*)&keys[base + 4 * t];
    lz += (k.x > T) ? __expf(key_to_float(k.x) - m) : 0.f;
    lz += (k.y > T) ? __expf(key_to_float(k.y) - m) : 0.f;
    lz += (k.z > T) ? __expf(key_to_float(k.z) - m) : 0.f;
    lz += (k.w > T) ? __expf(key_to_float(k.w) - m) : 0.f;
  }
#pragma unroll
  for (int off = 32; off > 0; off >>= 1) lz += __shfl_xor(lz, off);
  if (lane == 0) fred[wv] = lz;
  __syncthreads();
  const float Zi  = 1.0f / (fred[0] + fred[1] + fred[2] + fred[3] + (float)needK * eT);
  const float eTZ = eT * Zi;

#pragma unroll
  for (int base = 0; base < Ss; base += 1024) {
    const int i0 = base + 4 * t;
    const uint4 k = *(const uint4*)&keys[i0];
    float4 w;
    w.x = (k.x > T) ? __expf(key_to_float(k.x) - m) * Zi : ((k.x == T) ? eTZ : 0.f);
    w.y = (k.y > T) ? __expf(key_to_float(k.y) - m) * Zi : ((k.y == T) ? eTZ : 0.f);
    w.z = (k.z > T) ? __expf(key_to_float(k.z) - m) * Zi : ((k.z == T) ? eTZ : 0.f);
    w.w = (k.w > T) ? __expf(key_to_float(k.w) - m) * Zi : ((k.w == T) ? eTZ : 0.f);
    *(float4*)(rowp + i0) = w;
  }
}

}  // namespace

extern "C" void kernel_launch(void* const* d_in, const int* in_sizes, int n_in,
                              void* d_out_v, int out_size, void* d_ws, size_t ws_size,
                              hipStream_t stream)
{
  const float* query = (const float*)d_in[0];
  const float* key   = (const float*)d_in[1];
  const float* value = (const float*)d_in[2];
  const float* Wq = (const float*)d_in[3];  const float* bq = (const float*)d_in[4];
  const float* Wk = (const float*)d_in[5];  const float* bk = (const float*)d_in[6];
  const float* Wv = (const float*)d_in[7];  const float* bv = (const float*)d_in[8];
  const float* Wo = (const float*)d_in[9];  const float* bo = (const float*)d_in[10];

  float* d_out = (float*)d_out_v;
  float* outp  = d_out;                              // [B,S,D] f32
  float* wts   = d_out + (size_t)Bb * Ss * Dd;       // [B,H,S,S] f32

  const size_t PROJ = (size_t)MROWS * Dd;            // 4M elements
  const size_t DD2  = (size_t)Dd * Dd;               // 1M elements

  float*  ws    = (float*)d_ws;
  float*  Q     = ws;                                // f32 [BH][S][DK]  16 MB
  float*  Kw    = Q + PROJ;                          // f32 [BH][S][DK]  16 MB
  ushort* r3    = (ushort*)(Kw + PROJ);              // 8 MB region
  ushort* WqTh  = r3;                                //   Wq^T hi
  ushort* WqTl  = r3 + DD2;                          //   Wq^T lo
  ushort* WkTh  = r3 + 2 * DD2;                      //   Wk^T hi
  ushort* WkTl  = r3 + 3 * DD2;                      //   Wk^T lo
  ushort* vbf   = r3;                                //   (aliases after K proj)
  ushort* WvT   = r3 + 4 * DD2;                      // 2 MB
  ushort* WoT   = WvT + DD2;                         // 2 MB
  ushort* Vt    = WoT + DD2;                         // bf16 V^T [16][128][2048] 8 MB
  ushort* attnb = Vt + (size_t)BH * DKk * Ss;        // bf16 attn [4096][1024]  8 MB

  const dim3 blk(256);

  // weight prep
  transpose_split<<<dim3(32, 32), blk, 0, stream>>>(Wq, WqTh, WqTl);
  transpose_split<<<dim3(32, 32), blk, 0, stream>>>(Wk, WkTh, WkTl);
  transpose_bf16<<<dim3(32, 32), blk, 0, stream>>>(Wv, WvT);
  transpose_bf16<<<dim3(32, 32), blk, 0, stream>>>(Wo, WoT);

  // Q/K projections: split-bf16 MFMA (~f32 precision), out f32 [BH][S][DK]
  const dim3 gp(Dd / 128, MROWS / 128, 1);
  mfma_split_nt<0><<<gp, blk, 0, stream>>>(query, nullptr, WqTh, WqTl, bq, Q,
                                           MROWS, Dd, Dd);
  mfma_split_nt<0><<<gp, blk, 0, stream>>>(key, nullptr, WkTh, WkTl, bk, Kw,
                                           MROWS, Dd, Dd);

  // value -> bf16 (into the now-dead WqT/WkT region)
  conv_bf16<<<dim3((int)(PROJ / 1024)), blk, 0, stream>>>(value, vbf, (int)PROJ);

  // V projection (plain bf16 MFMA) -> V^T layout
  mfma_nt<1><<<dim3(Dd / 128, MROWS / 128, 1), blk, 0, stream>>>(
      vbf, WvT, bv, Vt, MROWS, Dd, Dd);

  // scores: split-bf16 MFMA, inline split of Q and K, out f32 * SCALE
  mfma_split_nt<1><<<dim3(Ss / 128, Ss / 128, BH), blk, 0, stream>>>(
      Q, Kw, nullptr, nullptr, nullptr, wts, Ss, Ss, DKk);

  // exact top-512 + softmax, in place
  topk_softmax<<<dim3(BH * Ss), blk, 0, stream>>>(wts);

  // PV (bf16 MFMA, stages f32 weights with inline conversion)
  mfma_nt<2><<<dim3(1, Ss / 128, BH), blk, 0, stream>>>(
      wts, Vt, nullptr, attnb, Ss, DKk, Ss);

  // output projection (bf16 MFMA, f32 out)
  mfma_nt<0><<<dim3(Dd / 128, MROWS / 128, 1), blk, 0, stream>>>(
      attnb, WoT, bo, outp, MROWS, Dd, Dd);
}